// Round 8
// baseline (317.162 us; speedup 1.0000x reference)
//
#include <hip/hip_runtime.h>
#include <hip/hip_bf16.h>
#include <stdint.h>

#define N_PTS 100000
#define INC 128
#define NSLOT 27
#define CAPP 8192                 // pairs per slot-bucket (expected ~620)

typedef float f32x4 __attribute__((ext_vector_type(4)));
typedef short bf16x8 __attribute__((ext_vector_type(8)));

// ---------------- workspace layout --------------------------------------
static const size_t OFF_WP   = 0;                                        // 27 slots frag-packed bf16
static const size_t SZ_WP    = (size_t)NSLOT * INC * INC * 2;
static const size_t OFF_WPRE = (OFF_WP + SZ_WP + 255) & ~(size_t)255;    // w_pre frag-packed bf16
static const size_t SZ_WPRE  = (size_t)INC * INC * 2;
static const size_t OFF_FIN  = (OFF_WPRE + SZ_WPRE + 255) & ~(size_t)255; // F_input bf16
static const size_t SZ_FIN   = (size_t)N_PTS * INC * 2;
static const size_t OFF_LOC  = (OFF_FIN + SZ_FIN + 255) & ~(size_t)255;   // self-conv f32 (by gemm)
static const size_t SZ_LOC   = (size_t)N_PTS * INC * 4;
static const size_t OFF_LOC2 = (OFF_LOC + SZ_LOC + 255) & ~(size_t)255;   // neighbor-conv f32 (atomics)
static const size_t SZ_LOC2  = (size_t)N_PTS * INC * 4;
static const size_t OFF_CNT  = (OFF_LOC2 + SZ_LOC2 + 255) & ~(size_t)255; // 26 bucket counters + [26]=ndl
static const size_t SZ_CNT   = 128;
static const size_t OFF_DST  = (OFF_CNT + SZ_CNT + 255) & ~(size_t)255;
static const size_t SZ_DST   = (size_t)26 * CAPP * 4;
static const size_t OFF_SRC  = (OFF_DST + SZ_DST + 255) & ~(size_t)255;
static const size_t SZ_SRC   = (size_t)26 * CAPP * 4;
static const size_t OFF_FLG  = (OFF_SRC + SZ_SRC + 255) & ~(size_t)255;   // per-point flags u8
static const size_t SZ_FLG   = (size_t)N_PTS;
static const size_t OFF_NDL  = (OFF_FLG + SZ_FLG + 255) & ~(size_t)255;   // needs-final point list
static const size_t SZ_NDL   = (size_t)N_PTS * 4;                          // total ~131 MB

#define PREP_BLOCKS 1792
#define SCAN_BLOCKS 391
#define MT64 1563                 // gemm-region blocks in fused kernel
#define PAIRB 256                 // pairs-region blocks in fused kernel

__device__ __forceinline__ float compute_pos3(float w0, float w1, float w2, float a,
                                              float cx, float cy, float cz) {
    return (cx * w0 + cy * w1 + cz * w2) * a;
}

// load 8 consecutive f32 and round to a bf16x8 MFMA fragment
__device__ __forceinline__ bf16x8 ld_cvt8(const float* __restrict__ p) {
    const float4 u = *(const float4*)p;
    const float4 v = *(const float4*)(p + 4);
    bf16x8 r;
    __hip_bfloat16* h = (__hip_bfloat16*)&r;
    h[0] = __float2bfloat16(u.x); h[1] = __float2bfloat16(u.y);
    h[2] = __float2bfloat16(u.z); h[3] = __float2bfloat16(u.w);
    h[4] = __float2bfloat16(v.x); h[5] = __float2bfloat16(v.y);
    h[6] = __float2bfloat16(v.z); h[7] = __float2bfloat16(v.w);
    return r;
}

// ---------------- K_front: weight pack (blocks < PREP_BLOCKS) + scan --------
// Scan region rebuilt: 27 neighbor loads batched into registers, then per-slot
// BALLOT compaction (1 global atomic per wave per non-empty slot, direct global
// write). No LDS, no barriers, no same-address atomic contention.
__global__ __launch_bounds__(256) void k_front(
        const float* __restrict__ w_pre, const float* __restrict__ w_conv,
        __hip_bfloat16* __restrict__ Wp, __hip_bfloat16* __restrict__ Wpre,
        const int* __restrict__ nbr_idx, const float* __restrict__ counts_v,
        int* __restrict__ cnt, int* __restrict__ dst, int* __restrict__ src,
        unsigned char* __restrict__ flg, int* __restrict__ ndl,
        float* __restrict__ loc2) {
    const int tid = threadIdx.x;

    if (blockIdx.x < PREP_BLOCKS) {
        // ---- prep part: pack weights (coalesced source reads) ----
        int i = blockIdx.x * 256 + tid;
        if (i < 16384) {                        // w_pre: B[n=d][k=c] = w_pre[d*128+c]
            int d = i >> 7, c = i & 127;
            int j = ((c >> 5) << 12) | ((d >> 4) << 9)
                  | (((((c >> 3) & 3) << 4) + (d & 15)) << 3) | (c & 7);
            Wpre[j] = __float2bfloat16(w_pre[i]);
        } else if (i < 16384 + NSLOT * 16384) { // w_conv: B[n=d][k=c] = w_conv[slot][c][d]
            int t = i - 16384;
            int slot = t >> 14, rem = t & 16383;
            int c = rem >> 7, d = rem & 127;
            int j = (slot << 14) | ((c >> 5) << 12) | ((d >> 4) << 9)
                  | (((((c >> 3) & 3) << 4) + (d & 15)) << 3) | (c & 7);
            Wp[j] = __float2bfloat16(w_conv[t]);
        }
        return;
    }

    // ---- scan region ----
    const int lane = tid & 63;
    const int p = (blockIdx.x - PREP_BLOCKS) * 256 + tid;
    const bool vp = p < N_PTS;

    float cv = vp ? counts_v[p] : 0.f;
    bool multi = cv > 1.5f;

    const int* nb = nbr_idx + (size_t)p * NSLOT;
    int nbr_r[NSLOT];
#pragma unroll                                 // 27 independent loads in flight
    for (int k = 0; k < NSLOT; ++k) nbr_r[k] = vp ? nb[k] : N_PTS;

    bool hn = false;
#pragma unroll
    for (int k = 0; k < NSLOT; ++k) {
        if (k == 13) continue;                 // self handled densely in gemm
        int m = nbr_r[k];
        bool valid = (m < N_PTS);
        hn = hn || valid;
        unsigned long long msk = __ballot(valid);
        if (msk) {                             // wave-uniform skip of empty slots
            int b = k < 13 ? k : k - 1;        // 0..25
            int basew = 0;
            if (lane == 0) basew = atomicAdd(&cnt[b], __popcll(msk));
            basew = __shfl(basew, 0);
            if (valid) {
                int gi = basew + __popcll(msk & ((1ull << lane) - 1ull));
                if (gi < CAPP) { dst[b * CAPP + gi] = p; src[b * CAPP + gi] = m; }
            }
        }
    }

    // flags: bit0 = needs k_final (multi or has occupied neighbor)
    bool ndv = vp && (hn || multi);
    if (vp) flg[p] = (unsigned char)(ndv ? 1 : 0);
    if (ndv) {                                 // zero loc2 row (pairs atomics land here)
        float4* row = (float4*)(loc2 + (size_t)p * INC);
#pragma unroll
        for (int i = 0; i < INC / 4; ++i) row[i] = make_float4(0.f, 0.f, 0.f, 0.f);
    }
    unsigned long long mb = __ballot(ndv);
    int basew2 = 0;
    if (lane == 0 && mb) basew2 = atomicAdd(&cnt[26], __popcll(mb));
    basew2 = __shfl(basew2, 0);
    if (ndv) ndl[basew2 + __popcll(mb & ((1ull << lane) - 1ull))] = p;
}

// ---------------- K_main: FUSED gemm-region + pairs-region ------------------
// blocks [0, MT64): merged pre_mix + self-conv GEMM with fused final.
// blocks [MT64, MT64+PAIRB): neighbor pairs (atomics into loc2, zeroed by
// k_front) -> co-scheduled, pairs latency hides under gemm compute.
__global__ __launch_bounds__(256, 3) void k_main(
        const float* __restrict__ F, const __hip_bfloat16* __restrict__ Wpre,
        const __hip_bfloat16* __restrict__ Wp, const unsigned char* __restrict__ flg,
        const float* __restrict__ g_pre, const float* __restrict__ b_pre,
        const float* __restrict__ g_local, const float* __restrict__ b_local,
        const float* __restrict__ g_norm, const float* __restrict__ b_norm,
        const int* __restrict__ cnt, const int* __restrict__ dst,
        const int* __restrict__ src,
        __hip_bfloat16* __restrict__ F_input, float* __restrict__ loc,
        float* __restrict__ loc2, float* __restrict__ outp) {
    __shared__ __hip_bfloat16 s_bf[4][16 * 136];   // per-wave F_input staging (gemm region)
    __shared__ float s_gp[INC], s_bp[INC], s_gl[INC], s_bl[INC], s_gn[INC], s_bn[INC];
    __shared__ int s_wre[27], s_cntb[26];          // pairs region

    const int tid = threadIdx.x, w = tid >> 6, lane = tid & 63;
    const int q = lane >> 4, l15 = lane & 15;

    if (blockIdx.x >= MT64) {
        // ================= pairs region =================
        const int pb = blockIdx.x - MT64;
        if (tid < 26) { int v = cnt[tid]; if (v > CAPP) v = CAPP; s_cntb[tid] = v; }
        __syncthreads();
        if (tid == 0) {                       // prefix over LDS (fast VALU loop)
            int accw = 0; s_wre[0] = 0;
            for (int b = 0; b < 26; ++b) { accw += (s_cntb[b] + 15) >> 4; s_wre[b + 1] = accw; }
        }
        __syncthreads();
        const int W = s_wre[26];
#pragma unroll 1
        for (int wvi = pb * 4 + w; wvi < W; wvi += PAIRB * 4) {
            int b = 0;
            while (wvi >= s_wre[b + 1]) ++b;       // wave-uniform, <=26 LDS reads
            int base = (wvi - s_wre[b]) << 4;
            int nB = s_cntb[b];
            int slot = b < 13 ? b : b + 1;
            const int* srcb = src + b * CAPP;
            const int* dstb = dst + b * CAPP;
            int mrow = (base + l15 < nB) ? srcb[base + l15] : 0;
            const bf16x8* Bp = (const bf16x8*)Wp + (size_t)slot * 2048;

            f32x4 acc[8];
#pragma unroll
            for (int j = 0; j < 8; ++j) acc[j] = (f32x4){0.f, 0.f, 0.f, 0.f};
#pragma unroll
            for (int ks = 0; ks < 4; ++ks) {
                bf16x8 a2 = ld_cvt8(F + (size_t)mrow * INC + ks * 32 + q * 8);
#pragma unroll
                for (int j = 0; j < 8; ++j)
                    acc[j] = __builtin_amdgcn_mfma_f32_16x16x32_bf16(
                        a2, Bp[(ks * 8 + j) * 64 + lane], acc[j], 0, 0, 0);
            }
            // all-lane scatter: q-group handles pairs base + q*4 + r
#pragma unroll
            for (int r = 0; r < 4; ++r) {
                int m = (q << 2) + r;
                int ri = base + m;
                if (ri < nB) {
                    int d = dstb[ri];
                    float* lp = loc2 + (size_t)d * INC + l15;
#pragma unroll
                    for (int j = 0; j < 8; ++j) atomicAdd(lp + (j << 4), acc[j][r]);
                }
            }
        }
        return;
    }

    // ================= gemm region =================
    const int p0 = blockIdx.x * 64;

    if (tid < INC) {
        s_gp[tid] = g_pre[tid];   s_bp[tid] = b_pre[tid];
        s_gl[tid] = g_local[tid]; s_bl[tid] = b_local[tid];
        s_gn[tid] = g_norm[tid];  s_bn[tid] = b_norm[tid];
    }
    __syncthreads();

    int grow = p0 + (w << 4) + l15;
    if (grow >= N_PTS) grow = N_PTS - 1;      // clamp; stores guarded

    const float* A = F + (size_t)grow * INC + q * 8;

    // prefetched flags: epilogue rows (q*4+r) and store rows (t*4+q)
    unsigned int fe = *(const unsigned int*)(flg + p0 + (w << 4) + (q << 2));
    unsigned char fs0 = flg[p0 + (w << 4) + q];
    unsigned char fs1 = flg[p0 + (w << 4) + 4 + q];
    unsigned char fs2 = flg[p0 + (w << 4) + 8 + q];
    unsigned char fs3 = flg[p0 + (w << 4) + 12 + q];

    bf16x8 a[4];
#pragma unroll
    for (int ks = 0; ks < 4; ++ks) a[ks] = ld_cvt8(A + ks * 32);

    // phase-split pipelined MFMA loop
    const bf16x8* BP = (const bf16x8*)Wpre;
    const bf16x8* BL = (const bf16x8*)Wp + (size_t)13 * 2048;
    f32x4 accP[8], accL[8];
#pragma unroll
    for (int j = 0; j < 8; ++j) {
        accP[j] = (f32x4){0.f, 0.f, 0.f, 0.f};
        accL[j] = (f32x4){0.f, 0.f, 0.f, 0.f};
    }
    bf16x8 bP[8], bL[8];
#pragma unroll
    for (int j = 0; j < 8; ++j) bP[j] = BP[j * 64 + lane];
#pragma unroll
    for (int ks = 0; ks < 4; ++ks) {
#pragma unroll
        for (int j = 0; j < 8; ++j) bL[j] = BL[(ks * 8 + j) * 64 + lane];
#pragma unroll
        for (int j = 0; j < 8; ++j)
            accP[j] = __builtin_amdgcn_mfma_f32_16x16x32_bf16(a[ks], bP[j], accP[j], 0, 0, 0);
        if (ks < 3) {
#pragma unroll
            for (int j = 0; j < 8; ++j) bP[j] = BP[((ks + 1) * 8 + j) * 64 + lane];
        }
#pragma unroll
        for (int j = 0; j < 8; ++j)
            accL[j] = __builtin_amdgcn_mfma_f32_16x16x32_bf16(a[ks], bL[j], accL[j], 0, 0, 0);
    }

    // merged epilogue per row
    __hip_bfloat16* sb = s_bf[w];
#pragma unroll
    for (int r = 0; r < 4; ++r) {
        int ri = (q << 2) + r;
        int p = p0 + (w << 4) + ri;
        int fl = (p < N_PTS) ? (int)((fe >> (r * 8)) & 1) : 1;

        float s = 0.f, ss = 0.f;
#pragma unroll
        for (int j = 0; j < 8; ++j) { float v = accP[j][r]; s += v; ss += v * v; }
#pragma unroll
        for (int m = 1; m < 16; m <<= 1) { s += __shfl_xor(s, m); ss += __shfl_xor(ss, m); }
        float mean = s * (1.f / 128.f);
        float rstd = rsqrtf(ss * (1.f / 128.f) - mean * mean + 1e-6f);

        float fj[8], sN = 0.f, ssN = 0.f, sL = 0.f, ssL = 0.f;
#pragma unroll
        for (int j = 0; j < 8; ++j) {
            int c = (j << 4) + l15;
            float fi = (accP[j][r] - mean) * rstd * s_gp[c] + s_bp[c];
            __hip_bfloat16 fb = __float2bfloat16(fi);
            sb[ri * 136 + c] = fb;
            float f = __bfloat162float(fb);
            fj[j] = f; sN += f; ssN += f * f;
            float v = accL[j][r]; sL += v; ssL += v * v;
        }
#pragma unroll
        for (int m = 1; m < 16; m <<= 1) {
            sN += __shfl_xor(sN, m); ssN += __shfl_xor(ssN, m);
            sL += __shfl_xor(sL, m); ssL += __shfl_xor(ssL, m);
        }
        float meanN = sN * (1.f / 128.f);
        float rstdN = rsqrtf(ssN * (1.f / 128.f) - meanN * meanN + 1e-6f);
        float meanL = sL * (1.f / 128.f);
        float rstdL = rsqrtf(ssL * (1.f / 128.f) - meanL * meanL + 1e-6f);

        if (p < N_PTS) {
            float* dp = fl ? (loc + (size_t)p * INC) : (outp + (size_t)p * INC);
#pragma unroll
            for (int j = 0; j < 8; ++j) {
                int c = (j << 4) + l15;
                float lvj = accL[j][r];
                float nn = (fj[j] - meanN) * rstdN * s_gn[c] + s_bn[c];
                float ll = (lvj - meanL) * rstdL * s_gl[c] + s_bl[c];
                float o = nn + ll; o = o > 0.f ? o : 0.f;
                dp[c] = fl ? lvj : o;
            }
        }
    }

    // F_input store only for needs-final rows
    {
        unsigned char fsv[4] = {fs0, fs1, fs2, fs3};
#pragma unroll
        for (int t = 0; t < 4; ++t) {
            int row = (t << 2) + q;
            int p = p0 + (w << 4) + row;
            if (p < N_PTS && (fsv[t] & 1)) {
                bf16x8 v = *(const bf16x8*)&sb[row * 136 + l15 * 8];
                *(bf16x8*)(F_input + (size_t)p * INC + l15 * 8) = v;
            }
        }
    }
}

// ---------------- K_final: sparse pass; vox via cellmate GATHER -------------
// 16 points per block (no serial point loop), grid-stride. local = loc + loc2.
// Gather keeps only fmv8[8] live; validity as bitmask, offsets recomputed.
__global__ __launch_bounds__(256) void k_final(
        const __hip_bfloat16* __restrict__ F_input, const float* __restrict__ loc,
        const float* __restrict__ loc2,
        const int* __restrict__ nbr_idx, const int* __restrict__ coords,
        const float* __restrict__ counts_v,
        const float* __restrict__ w_pos, const float* __restrict__ alpha,
        const float* __restrict__ g_local, const float* __restrict__ b_local,
        const float* __restrict__ g_norm, const float* __restrict__ b_norm,
        const int* __restrict__ cnt, const int* __restrict__ ndl,
        float* __restrict__ out) {
    const int tid = threadIdx.x, g = tid >> 4, l15 = tid & 15;
    const int c0 = l15 * 8;
    const int nd = cnt[26];
    if (blockIdx.x * 16 >= nd) return;

    float wpv[24], pa[8], gl[8], bl[8], gn[8], bn[8];
#pragma unroll
    for (int t = 0; t < 6; ++t) ((float4*)wpv)[t] = ((const float4*)(w_pos + c0 * 3))[t];
#pragma unroll
    for (int t = 0; t < 2; ++t) {
        ((float4*)pa)[t] = ((const float4*)(alpha   + c0))[t];
        ((float4*)gl)[t] = ((const float4*)(g_local + c0))[t];
        ((float4*)bl)[t] = ((const float4*)(b_local + c0))[t];
        ((float4*)gn)[t] = ((const float4*)(g_norm  + c0))[t];
        ((float4*)bn)[t] = ((const float4*)(b_norm  + c0))[t];
    }

    for (int base = blockIdx.x * 16; base < nd; base += gridDim.x * 16) {
        int idx = base + g;
        if (idx >= nd) continue;
        int p = ndl[idx];

        float lv[8], s = 0.f, ss = 0.f;
        float4 la0 = *(const float4*)(loc  + (size_t)p * INC + c0);
        float4 la1 = *(const float4*)(loc  + (size_t)p * INC + c0 + 4);
        float4 lb0 = *(const float4*)(loc2 + (size_t)p * INC + c0);
        float4 lb1 = *(const float4*)(loc2 + (size_t)p * INC + c0 + 4);
        lv[0] = la0.x + lb0.x; lv[1] = la0.y + lb0.y;
        lv[2] = la0.z + lb0.z; lv[3] = la0.w + lb0.w;
        lv[4] = la1.x + lb1.x; lv[5] = la1.y + lb1.y;
        lv[6] = la1.z + lb1.z; lv[7] = la1.w + lb1.w;
#pragma unroll
        for (int j = 0; j < 8; ++j) { s += lv[j]; ss += lv[j] * lv[j]; }
#pragma unroll
        for (int m = 1; m < 16; m <<= 1) { s += __shfl_xor(s, m); ss += __shfl_xor(ss, m); }
        float meanL = s * (1.f / 128.f);
        float rstdL = rsqrtf(ss * (1.f / 128.f) - meanL * meanL + 1e-6f);

        float cv = counts_v[p];
        bool multi = cv > 1.5f;
        int ix = coords[p * 3 + 0], iy = coords[p * 3 + 1], iz = coords[p * 3 + 2];
        float cx = (float)ix, cy = (float)iy, cz = (float)iz;

        bf16x8 fbv = *(const bf16x8*)(F_input + (size_t)p * INC + c0);

        float psO[8], snO[8], csO[8], fO[8];
#pragma unroll
        for (int j = 0; j < 8; ++j) {
            fO[j] = __bfloat162float(((__hip_bfloat16*)&fbv)[j]);
            psO[j] = compute_pos3(wpv[j * 3], wpv[j * 3 + 1], wpv[j * 3 + 2], pa[j], cx, cy, cz);
            snO[j] = __sinf(psO[j]); csO[j] = __cosf(psO[j]);
        }

        float v0[8], v1[8], v2[8];
        if (multi) {
            float invc = 1.f / cv;
            int ox = (ix & 1) ? -1 : 1, oy = (iy & 1) ? -1 : 1, oz = (iz & 1) ? -1 : 1;
            const int* nb = nbr_idx + (size_t)p * NSLOT;
            // phase 1: all 7 cellmate indices + rows batched (self = fbv)
            unsigned vmask = 1u;
            bf16x8 fmv8[8];
            fmv8[0] = fbv;
#pragma unroll
            for (int e = 1; e < 8; ++e) {
                int dx = (e & 4) ? ox : 0, dy = (e & 2) ? oy : 0, dz = (e & 1) ? oz : 0;
                int m = nb[(dx + 1) * 9 + (dy + 1) * 3 + (dz + 1)];
                bool ok = m < N_PTS;
                if (ok) vmask |= (1u << e);
                int mc = ok ? m : p;
                fmv8[e] = *(const bf16x8*)(F_input + (size_t)mc * INC + c0);
            }
#pragma unroll
            for (int j = 0; j < 8; ++j) { v0[j] = 0.f; v1[j] = 0.f; v2[j] = 0.f; }
            // phase 2: masked accumulation (wt=0 contributes exactly 0)
#pragma unroll
            for (int e = 0; e < 8; ++e) {
                float wt = ((vmask >> e) & 1u) ? 1.f : 0.f;
                int dx = (e & 4) ? ox : 0, dy = (e & 2) ? oy : 0, dz = (e & 1) ? oz : 0;
                float mx = cx + (float)dx, my = cy + (float)dy, mz = cz + (float)dz;
#pragma unroll
                for (int j = 0; j < 8; ++j) {
                    float fm = wt * __bfloat162float(((__hip_bfloat16*)&fmv8[e])[j]);
                    float ps = compute_pos3(wpv[j * 3], wpv[j * 3 + 1], wpv[j * 3 + 2], pa[j],
                                            mx, my, mz);
                    v0[j] += fm * __cosf(ps);
                    v1[j] += fm * __sinf(ps);
                    v2[j] += fm * ps;
                }
            }
#pragma unroll
            for (int j = 0; j < 8; ++j) { v0[j] *= invc; v1[j] *= invc; v2[j] *= invc; }
        } else {
#pragma unroll
            for (int j = 0; j < 8; ++j) {
                v0[j] = fO[j] * csO[j]; v1[j] = fO[j] * snO[j]; v2[j] = fO[j] * psO[j];
            }
        }

        float nv[8], s2 = 0.f, ss2 = 0.f;
#pragma unroll
        for (int j = 0; j < 8; ++j) {
            float nw = v0[j] * csO[j] + v1[j] * snO[j] + v2[j] - fO[j] * psO[j];
            nv[j] = nw; s2 += nw; ss2 += nw * nw;
        }
#pragma unroll
        for (int m = 1; m < 16; m <<= 1) { s2 += __shfl_xor(s2, m); ss2 += __shfl_xor(ss2, m); }
        float meanN = s2 * (1.f / 128.f);
        float rstdN = rsqrtf(ss2 * (1.f / 128.f) - meanN * meanN + 1e-6f);
        float ov[8];
#pragma unroll
        for (int j = 0; j < 8; ++j) {
            float nn = (nv[j] - meanN) * rstdN * gn[j] + bn[j];
            float ll = (lv[j] - meanL) * rstdL * gl[j] + bl[j];
            float o = nn + ll;
            ov[j] = o > 0.f ? o : 0.f;
        }
        float4* op = (float4*)(out + (size_t)p * INC + c0);
        op[0] = ((float4*)ov)[0];
        op[1] = ((float4*)ov)[1];
    }
}

// ---------------- host launcher ---------------------------------------------
extern "C" void kernel_launch(void* const* d_in, const int* in_sizes, int n_in,
                              void* d_out, int out_size, void* d_ws, size_t ws_size,
                              hipStream_t stream) {
    (void)in_sizes; (void)n_in; (void)out_size; (void)ws_size;
    const float* F        = (const float*)d_in[0];
    const int*   coords   = (const int*)d_in[1];
    const int*   nbr      = (const int*)d_in[2];
    const float* counts_v = (const float*)d_in[4];
    const float* alpha    = (const float*)d_in[6];
    const float* w_pos    = (const float*)d_in[7];
    const float* w_pre    = (const float*)d_in[8];
    const float* g_pre    = (const float*)d_in[9];
    const float* b_pre    = (const float*)d_in[10];
    const float* w_conv   = (const float*)d_in[11];
    const float* g_local  = (const float*)d_in[12];
    const float* b_local  = (const float*)d_in[13];
    const float* g_norm   = (const float*)d_in[14];
    const float* b_norm   = (const float*)d_in[15];
    float* out = (float*)d_out;

    char* ws = (char*)d_ws;
    __hip_bfloat16* Wp      = (__hip_bfloat16*)(ws + OFF_WP);
    __hip_bfloat16* Wpre    = (__hip_bfloat16*)(ws + OFF_WPRE);
    __hip_bfloat16* F_input = (__hip_bfloat16*)(ws + OFF_FIN);
    float*          loc     = (float*)(ws + OFF_LOC);
    float*          loc2    = (float*)(ws + OFF_LOC2);
    int*            cnt     = (int*)(ws + OFF_CNT);
    int*            dstb    = (int*)(ws + OFF_DST);
    int*            srcb    = (int*)(ws + OFF_SRC);
    unsigned char*  flg     = (unsigned char*)(ws + OFF_FLG);
    int*            ndl     = (int*)(ws + OFF_NDL);

    hipMemsetAsync(cnt, 0, SZ_CNT, stream);
    k_front<<<PREP_BLOCKS + SCAN_BLOCKS, 256, 0, stream>>>(
        w_pre, w_conv, Wp, Wpre, nbr, counts_v, cnt, dstb, srcb, flg, ndl, loc2);
    k_main<<<MT64 + PAIRB, 256, 0, stream>>>(
        F, Wpre, Wp, flg, g_pre, b_pre, g_local, b_local, g_norm, b_norm,
        cnt, dstb, srcb, F_input, loc, loc2, out);
    k_final<<<1024, 256, 0, stream>>>(F_input, loc, loc2, nbr, coords, counts_v,
                                      w_pos, alpha, g_local, b_local, g_norm, b_norm,
                                      cnt, ndl, out);
}

// Round 9
// 278.501 us; speedup vs baseline: 1.1388x; 1.1388x over previous
//
#include <hip/hip_runtime.h>
#include <hip/hip_bf16.h>
#include <hip/hip_cooperative_groups.h>
#include <stdint.h>

namespace cg = cooperative_groups;

#define N_PTS 100000
#define INC 128
#define NSLOT 27
#define CAPP 8192                 // pairs per slot-bucket (expected ~620)

typedef float f32x4 __attribute__((ext_vector_type(4)));
typedef short bf16x8 __attribute__((ext_vector_type(8)));

// ---------------- workspace layout --------------------------------------
static const size_t OFF_WP   = 0;                                        // 27 slots frag-packed bf16
static const size_t SZ_WP    = (size_t)NSLOT * INC * INC * 2;
static const size_t OFF_WPRE = (OFF_WP + SZ_WP + 255) & ~(size_t)255;    // w_pre frag-packed bf16
static const size_t SZ_WPRE  = (size_t)INC * INC * 2;
static const size_t OFF_FIN  = (OFF_WPRE + SZ_WPRE + 255) & ~(size_t)255; // F_input bf16
static const size_t SZ_FIN   = (size_t)N_PTS * INC * 2;
static const size_t OFF_LOC  = (OFF_FIN + SZ_FIN + 255) & ~(size_t)255;   // self-conv f32 (by gemm)
static const size_t SZ_LOC   = (size_t)N_PTS * INC * 4;
static const size_t OFF_LOC2 = (OFF_LOC + SZ_LOC + 255) & ~(size_t)255;   // neighbor-conv f32 (atomics)
static const size_t SZ_LOC2  = (size_t)N_PTS * INC * 4;
static const size_t OFF_CNT  = (OFF_LOC2 + SZ_LOC2 + 255) & ~(size_t)255; // 26 bucket counters + [26]=ndl
static const size_t SZ_CNT   = 128;
static const size_t OFF_DST  = (OFF_CNT + SZ_CNT + 255) & ~(size_t)255;
static const size_t SZ_DST   = (size_t)26 * CAPP * 4;
static const size_t OFF_SRC  = (OFF_DST + SZ_DST + 255) & ~(size_t)255;
static const size_t SZ_SRC   = (size_t)26 * CAPP * 4;
static const size_t OFF_FLG  = (OFF_SRC + SZ_SRC + 255) & ~(size_t)255;   // per-point flags u8
static const size_t SZ_FLG   = (size_t)N_PTS;
static const size_t OFF_NDL  = (OFF_FLG + SZ_FLG + 255) & ~(size_t)255;   // needs-final point list
static const size_t SZ_NDL   = (size_t)N_PTS * 4;                          // total ~131 MB

#define PREP_BLOCKS 1792
#define SCAN_BLOCKS 391
#define MT64 1563                 // gemm tasks
#define PAIRB 256                 // pairs tasks

struct SharedBlk {
    unsigned long long s_msk[4][26];   // per-wave per-slot validity masks
    unsigned long long s_ndm[4];       // per-wave needs-final masks
    __hip_bfloat16 s_bf[4][16 * 136];  // per-wave F_input staging (gemm)
    float s_gp[INC], s_bp[INC], s_gl[INC], s_bl[INC], s_gn[INC], s_bn[INC];
    int s_wre[27], s_cntb[26];         // pairs wave-range prefix
    int s_base[26];                    // bucket block bases
    int s_nbase;                       // ndl block base
};                                     // ~21.7 KB

__device__ __forceinline__ float compute_pos3(float w0, float w1, float w2, float a,
                                              float cx, float cy, float cz) {
    return (cx * w0 + cy * w1 + cz * w2) * a;
}

__device__ __forceinline__ bf16x8 ld_cvt8(const float* __restrict__ p) {
    const float4 u = *(const float4*)p;
    const float4 v = *(const float4*)(p + 4);
    bf16x8 r;
    __hip_bfloat16* h = (__hip_bfloat16*)&r;
    h[0] = __float2bfloat16(u.x); h[1] = __float2bfloat16(u.y);
    h[2] = __float2bfloat16(u.z); h[3] = __float2bfloat16(u.w);
    h[4] = __float2bfloat16(v.x); h[5] = __float2bfloat16(v.y);
    h[6] = __float2bfloat16(v.z); h[7] = __float2bfloat16(v.w);
    return r;
}

// ---------------- phase pieces (shared by coop + fallback) ------------------

__device__ __forceinline__ void do_prep(int task,
        const float* __restrict__ w_pre, const float* __restrict__ w_conv,
        __hip_bfloat16* __restrict__ Wp, __hip_bfloat16* __restrict__ Wpre) {
    int i = task * 256 + threadIdx.x;
    if (i < 16384) {                        // w_pre: B[n=d][k=c] = w_pre[d*128+c]
        int d = i >> 7, c = i & 127;
        int j = ((c >> 5) << 12) | ((d >> 4) << 9)
              | (((((c >> 3) & 3) << 4) + (d & 15)) << 3) | (c & 7);
        Wpre[j] = __float2bfloat16(w_pre[i]);
    } else if (i < 16384 + NSLOT * 16384) { // w_conv: B[n=d][k=c] = w_conv[slot][c][d]
        int t = i - 16384;
        int slot = t >> 14, rem = t & 16383;
        int c = rem >> 7, d = rem & 127;
        int j = (slot << 14) | ((c >> 5) << 12) | ((d >> 4) << 9)
              | (((((c >> 3) & 3) << 4) + (d & 15)) << 3) | (c & 7);
        Wp[j] = __float2bfloat16(w_conv[t]);
    }
}

// block-staged ballot scan: per-wave ballots -> LDS masks -> 26 PARALLEL
// block-level global atomics -> direct scatter. No per-thread atomic chains.
__device__ void do_scan(int chunk, SharedBlk* sh,
        const int* __restrict__ nbr_idx, const float* __restrict__ counts_v,
        int* __restrict__ cnt, int* __restrict__ dst, int* __restrict__ src,
        unsigned char* __restrict__ flg, int* __restrict__ ndl,
        float* __restrict__ loc2) {
    const int tid = threadIdx.x, w = tid >> 6, lane = tid & 63;
    const int p = chunk * 256 + tid;
    const bool vp = p < N_PTS;

    float cv = vp ? counts_v[p] : 0.f;
    bool multi = cv > 1.5f;

    const int* nb = nbr_idx + (size_t)p * NSLOT;
    int nbr_r[NSLOT];
#pragma unroll
    for (int k = 0; k < NSLOT; ++k) nbr_r[k] = vp ? nb[k] : N_PTS;

    bool hn = false;
#pragma unroll
    for (int k = 0; k < NSLOT; ++k) {
        if (k == 13) continue;
        bool valid = nbr_r[k] < N_PTS;
        hn = hn || valid;
        unsigned long long msk = __ballot(valid);
        int b = k < 13 ? k : k - 1;
        if (lane == 0) sh->s_msk[w][b] = msk;
    }
    bool ndv = vp && (hn || multi);
    unsigned long long ndm = __ballot(ndv);
    if (lane == 0) sh->s_ndm[w] = ndm;
    __syncthreads();

    if (tid < 26) {
        int tot = 0;
#pragma unroll
        for (int ww = 0; ww < 4; ++ww) tot += __popcll(sh->s_msk[ww][tid]);
        sh->s_base[tid] = tot ? atomicAdd(&cnt[tid], tot) : 0;
    } else if (tid == 32) {
        int tot = 0;
#pragma unroll
        for (int ww = 0; ww < 4; ++ww) tot += __popcll(sh->s_ndm[ww]);
        sh->s_nbase = tot ? atomicAdd(&cnt[26], tot) : 0;
    }
    __syncthreads();

    // scatter buckets
#pragma unroll
    for (int k = 0; k < NSLOT; ++k) {
        if (k == 13) continue;
        int b = k < 13 ? k : k - 1;
        if (nbr_r[k] < N_PTS) {
            unsigned long long msk = sh->s_msk[w][b];
            int pre = 0;
            for (int ww = 0; ww < w; ++ww) pre += __popcll(sh->s_msk[ww][b]);
            int gi = sh->s_base[b] + pre + __popcll(msk & ((1ull << lane) - 1ull));
            if (gi < CAPP) { dst[b * CAPP + gi] = p; src[b * CAPP + gi] = nbr_r[k]; }
        }
    }

    if (vp) flg[p] = (unsigned char)(ndv ? 1 : 0);
    if (ndv) {
        float4* row = (float4*)(loc2 + (size_t)p * INC);
#pragma unroll
        for (int i = 0; i < INC / 4; ++i) row[i] = make_float4(0.f, 0.f, 0.f, 0.f);
        unsigned long long m2 = sh->s_ndm[w];
        int pre = 0;
        for (int ww = 0; ww < w; ++ww) pre += __popcll(sh->s_ndm[ww]);
        ndl[sh->s_nbase + pre + __popcll(m2 & ((1ull << lane) - 1ull))] = p;
    }
}

__device__ __forceinline__ void load_params(SharedBlk* sh,
        const float* g_pre, const float* b_pre, const float* g_local,
        const float* b_local, const float* g_norm, const float* b_norm) {
    int tid = threadIdx.x;
    if (tid < INC) {
        sh->s_gp[tid] = g_pre[tid];   sh->s_bp[tid] = b_pre[tid];
        sh->s_gl[tid] = g_local[tid]; sh->s_bl[tid] = b_local[tid];
        sh->s_gn[tid] = g_norm[tid];  sh->s_bn[tid] = b_norm[tid];
    }
}

// merged pre_mix + self-conv GEMM with fused final (params preloaded in sh)
__device__ void do_gemm(int task, SharedBlk* sh,
        const float* __restrict__ F, const __hip_bfloat16* __restrict__ Wpre,
        const __hip_bfloat16* __restrict__ Wp, const unsigned char* __restrict__ flg,
        __hip_bfloat16* __restrict__ F_input, float* __restrict__ loc,
        float* __restrict__ outp) {
    const int tid = threadIdx.x, w = tid >> 6, lane = tid & 63;
    const int q = lane >> 4, l15 = lane & 15;
    const int p0 = task * 64;

    int grow = p0 + (w << 4) + l15;
    if (grow >= N_PTS) grow = N_PTS - 1;

    const float* A = F + (size_t)grow * INC + q * 8;

    unsigned int fe = *(const unsigned int*)(flg + p0 + (w << 4) + (q << 2));
    unsigned char fs0 = flg[p0 + (w << 4) + q];
    unsigned char fs1 = flg[p0 + (w << 4) + 4 + q];
    unsigned char fs2 = flg[p0 + (w << 4) + 8 + q];
    unsigned char fs3 = flg[p0 + (w << 4) + 12 + q];

    bf16x8 a[4];
#pragma unroll
    for (int ks = 0; ks < 4; ++ks) a[ks] = ld_cvt8(A + ks * 32);

    const bf16x8* BP = (const bf16x8*)Wpre;
    const bf16x8* BL = (const bf16x8*)Wp + (size_t)13 * 2048;
    f32x4 accP[8], accL[8];
#pragma unroll
    for (int j = 0; j < 8; ++j) {
        accP[j] = (f32x4){0.f, 0.f, 0.f, 0.f};
        accL[j] = (f32x4){0.f, 0.f, 0.f, 0.f};
    }
    bf16x8 bP[8], bL[8];
#pragma unroll
    for (int j = 0; j < 8; ++j) bP[j] = BP[j * 64 + lane];
#pragma unroll
    for (int ks = 0; ks < 4; ++ks) {
#pragma unroll
        for (int j = 0; j < 8; ++j) bL[j] = BL[(ks * 8 + j) * 64 + lane];
#pragma unroll
        for (int j = 0; j < 8; ++j)
            accP[j] = __builtin_amdgcn_mfma_f32_16x16x32_bf16(a[ks], bP[j], accP[j], 0, 0, 0);
        if (ks < 3) {
#pragma unroll
            for (int j = 0; j < 8; ++j) bP[j] = BP[((ks + 1) * 8 + j) * 64 + lane];
        }
#pragma unroll
        for (int j = 0; j < 8; ++j)
            accL[j] = __builtin_amdgcn_mfma_f32_16x16x32_bf16(a[ks], bL[j], accL[j], 0, 0, 0);
    }

    __hip_bfloat16* sb = sh->s_bf[w];
#pragma unroll
    for (int r = 0; r < 4; ++r) {
        int ri = (q << 2) + r;
        int p = p0 + (w << 4) + ri;
        int fl = (p < N_PTS) ? (int)((fe >> (r * 8)) & 1) : 1;

        float s = 0.f, ss = 0.f;
#pragma unroll
        for (int j = 0; j < 8; ++j) { float v = accP[j][r]; s += v; ss += v * v; }
#pragma unroll
        for (int m = 1; m < 16; m <<= 1) { s += __shfl_xor(s, m); ss += __shfl_xor(ss, m); }
        float mean = s * (1.f / 128.f);
        float rstd = rsqrtf(ss * (1.f / 128.f) - mean * mean + 1e-6f);

        float fj[8], sN = 0.f, ssN = 0.f, sL = 0.f, ssL = 0.f;
#pragma unroll
        for (int j = 0; j < 8; ++j) {
            int c = (j << 4) + l15;
            float fi = (accP[j][r] - mean) * rstd * sh->s_gp[c] + sh->s_bp[c];
            __hip_bfloat16 fb = __float2bfloat16(fi);
            sb[ri * 136 + c] = fb;
            float f = __bfloat162float(fb);
            fj[j] = f; sN += f; ssN += f * f;
            float v = accL[j][r]; sL += v; ssL += v * v;
        }
#pragma unroll
        for (int m = 1; m < 16; m <<= 1) {
            sN += __shfl_xor(sN, m); ssN += __shfl_xor(ssN, m);
            sL += __shfl_xor(sL, m); ssL += __shfl_xor(ssL, m);
        }
        float meanN = sN * (1.f / 128.f);
        float rstdN = rsqrtf(ssN * (1.f / 128.f) - meanN * meanN + 1e-6f);
        float meanL = sL * (1.f / 128.f);
        float rstdL = rsqrtf(ssL * (1.f / 128.f) - meanL * meanL + 1e-6f);

        if (p < N_PTS) {
            float* dp = fl ? (loc + (size_t)p * INC) : (outp + (size_t)p * INC);
#pragma unroll
            for (int j = 0; j < 8; ++j) {
                int c = (j << 4) + l15;
                float lvj = accL[j][r];
                float nn = (fj[j] - meanN) * rstdN * sh->s_gn[c] + sh->s_bn[c];
                float ll = (lvj - meanL) * rstdL * sh->s_gl[c] + sh->s_bl[c];
                float o = nn + ll; o = o > 0.f ? o : 0.f;
                dp[c] = fl ? lvj : o;
            }
        }
    }

    unsigned char fsv[4] = {fs0, fs1, fs2, fs3};
#pragma unroll
    for (int t = 0; t < 4; ++t) {
        int row = (t << 2) + q;
        int p = p0 + (w << 4) + row;
        if (p < N_PTS && (fsv[t] & 1)) {
            bf16x8 v = *(const bf16x8*)&sb[row * 136 + l15 * 8];
            *(bf16x8*)(F_input + (size_t)p * INC + l15 * 8) = v;
        }
    }
}

__device__ void do_pairs(int pb, SharedBlk* sh,
        const float* __restrict__ F, const __hip_bfloat16* __restrict__ Wp,
        const int* __restrict__ cnt, const int* __restrict__ dst,
        const int* __restrict__ src, float* __restrict__ loc2) {
    const int tid = threadIdx.x, w = tid >> 6, lane = tid & 63;
    const int q = lane >> 4, l15 = lane & 15;

    if (tid < 26) { int v = cnt[tid]; if (v > CAPP) v = CAPP; sh->s_cntb[tid] = v; }
    __syncthreads();
    if (tid == 0) {
        int accw = 0; sh->s_wre[0] = 0;
        for (int b = 0; b < 26; ++b) { accw += (sh->s_cntb[b] + 15) >> 4; sh->s_wre[b + 1] = accw; }
    }
    __syncthreads();
    const int W = sh->s_wre[26];
#pragma unroll 1
    for (int wvi = pb * 4 + w; wvi < W; wvi += PAIRB * 4) {
        int b = 0;
        while (wvi >= sh->s_wre[b + 1]) ++b;
        int base = (wvi - sh->s_wre[b]) << 4;
        int nB = sh->s_cntb[b];
        int slot = b < 13 ? b : b + 1;
        const int* srcb = src + b * CAPP;
        const int* dstb = dst + b * CAPP;
        int mrow = (base + l15 < nB) ? srcb[base + l15] : 0;
        const bf16x8* Bp = (const bf16x8*)Wp + (size_t)slot * 2048;

        f32x4 acc[8];
#pragma unroll
        for (int j = 0; j < 8; ++j) acc[j] = (f32x4){0.f, 0.f, 0.f, 0.f};
#pragma unroll
        for (int ks = 0; ks < 4; ++ks) {
            bf16x8 a2 = ld_cvt8(F + (size_t)mrow * INC + ks * 32 + q * 8);
#pragma unroll
            for (int j = 0; j < 8; ++j)
                acc[j] = __builtin_amdgcn_mfma_f32_16x16x32_bf16(
                    a2, Bp[(ks * 8 + j) * 64 + lane], acc[j], 0, 0, 0);
        }
#pragma unroll
        for (int r = 0; r < 4; ++r) {
            int m = (q << 2) + r;
            int ri = base + m;
            if (ri < nB) {
                int d = dstb[ri];
                float* lp = loc2 + (size_t)d * INC + l15;
#pragma unroll
                for (int j = 0; j < 8; ++j) atomicAdd(lp + (j << 4), acc[j][r]);
            }
        }
    }
}

__device__ void do_final(int task, int nd,
        const __hip_bfloat16* __restrict__ F_input, const float* __restrict__ loc,
        const float* __restrict__ loc2,
        const int* __restrict__ nbr_idx, const int* __restrict__ coords,
        const float* __restrict__ counts_v,
        const float* __restrict__ w_pos, const float* __restrict__ alpha,
        const float* __restrict__ g_local, const float* __restrict__ b_local,
        const float* __restrict__ g_norm, const float* __restrict__ b_norm,
        const int* __restrict__ ndl, float* __restrict__ out) {
    const int tid = threadIdx.x, g = tid >> 4, l15 = tid & 15;
    const int c0 = l15 * 8;
    int idx = task * 16 + g;
    if (idx >= nd) return;
    int p = ndl[idx];

    float wpv[24], pa[8], gl[8], bl[8], gn[8], bn[8];
#pragma unroll
    for (int t = 0; t < 6; ++t) ((float4*)wpv)[t] = ((const float4*)(w_pos + c0 * 3))[t];
#pragma unroll
    for (int t = 0; t < 2; ++t) {
        ((float4*)pa)[t] = ((const float4*)(alpha   + c0))[t];
        ((float4*)gl)[t] = ((const float4*)(g_local + c0))[t];
        ((float4*)bl)[t] = ((const float4*)(b_local + c0))[t];
        ((float4*)gn)[t] = ((const float4*)(g_norm  + c0))[t];
        ((float4*)bn)[t] = ((const float4*)(b_norm  + c0))[t];
    }

    float lv[8], s = 0.f, ss = 0.f;
    float4 la0 = *(const float4*)(loc  + (size_t)p * INC + c0);
    float4 la1 = *(const float4*)(loc  + (size_t)p * INC + c0 + 4);
    float4 lb0 = *(const float4*)(loc2 + (size_t)p * INC + c0);
    float4 lb1 = *(const float4*)(loc2 + (size_t)p * INC + c0 + 4);
    lv[0] = la0.x + lb0.x; lv[1] = la0.y + lb0.y;
    lv[2] = la0.z + lb0.z; lv[3] = la0.w + lb0.w;
    lv[4] = la1.x + lb1.x; lv[5] = la1.y + lb1.y;
    lv[6] = la1.z + lb1.z; lv[7] = la1.w + lb1.w;
#pragma unroll
    for (int j = 0; j < 8; ++j) { s += lv[j]; ss += lv[j] * lv[j]; }
#pragma unroll
    for (int m = 1; m < 16; m <<= 1) { s += __shfl_xor(s, m); ss += __shfl_xor(ss, m); }
    float meanL = s * (1.f / 128.f);
    float rstdL = rsqrtf(ss * (1.f / 128.f) - meanL * meanL + 1e-6f);

    float cv = counts_v[p];
    bool multi = cv > 1.5f;
    int ix = coords[p * 3 + 0], iy = coords[p * 3 + 1], iz = coords[p * 3 + 2];
    float cx = (float)ix, cy = (float)iy, cz = (float)iz;

    bf16x8 fbv = *(const bf16x8*)(F_input + (size_t)p * INC + c0);

    float psO[8], snO[8], csO[8], fO[8];
#pragma unroll
    for (int j = 0; j < 8; ++j) {
        fO[j] = __bfloat162float(((__hip_bfloat16*)&fbv)[j]);
        psO[j] = compute_pos3(wpv[j * 3], wpv[j * 3 + 1], wpv[j * 3 + 2], pa[j], cx, cy, cz);
        snO[j] = __sinf(psO[j]); csO[j] = __cosf(psO[j]);
    }

    float v0[8], v1[8], v2[8];
    if (multi) {
        float invc = 1.f / cv;
        int ox = (ix & 1) ? -1 : 1, oy = (iy & 1) ? -1 : 1, oz = (iz & 1) ? -1 : 1;
        const int* nb = nbr_idx + (size_t)p * NSLOT;
        unsigned vmask = 1u;
        bf16x8 fmv8[8];
        fmv8[0] = fbv;
#pragma unroll
        for (int e = 1; e < 8; ++e) {
            int dx = (e & 4) ? ox : 0, dy = (e & 2) ? oy : 0, dz = (e & 1) ? oz : 0;
            int m = nb[(dx + 1) * 9 + (dy + 1) * 3 + (dz + 1)];
            bool ok = m < N_PTS;
            if (ok) vmask |= (1u << e);
            int mc = ok ? m : p;
            fmv8[e] = *(const bf16x8*)(F_input + (size_t)mc * INC + c0);
        }
#pragma unroll
        for (int j = 0; j < 8; ++j) { v0[j] = 0.f; v1[j] = 0.f; v2[j] = 0.f; }
#pragma unroll
        for (int e = 0; e < 8; ++e) {
            float wt = ((vmask >> e) & 1u) ? 1.f : 0.f;
            int dx = (e & 4) ? ox : 0, dy = (e & 2) ? oy : 0, dz = (e & 1) ? oz : 0;
            float mx = cx + (float)dx, my = cy + (float)dy, mz = cz + (float)dz;
#pragma unroll
            for (int j = 0; j < 8; ++j) {
                float fm = wt * __bfloat162float(((__hip_bfloat16*)&fmv8[e])[j]);
                float ps = compute_pos3(wpv[j * 3], wpv[j * 3 + 1], wpv[j * 3 + 2], pa[j],
                                        mx, my, mz);
                v0[j] += fm * __cosf(ps);
                v1[j] += fm * __sinf(ps);
                v2[j] += fm * ps;
            }
        }
#pragma unroll
        for (int j = 0; j < 8; ++j) { v0[j] *= invc; v1[j] *= invc; v2[j] *= invc; }
    } else {
#pragma unroll
        for (int j = 0; j < 8; ++j) {
            v0[j] = fO[j] * csO[j]; v1[j] = fO[j] * snO[j]; v2[j] = fO[j] * psO[j];
        }
    }

    float nv[8], s2 = 0.f, ss2 = 0.f;
#pragma unroll
    for (int j = 0; j < 8; ++j) {
        float nw = v0[j] * csO[j] + v1[j] * snO[j] + v2[j] - fO[j] * psO[j];
        nv[j] = nw; s2 += nw; ss2 += nw * nw;
    }
#pragma unroll
    for (int m = 1; m < 16; m <<= 1) { s2 += __shfl_xor(s2, m); ss2 += __shfl_xor(ss2, m); }
    float meanN = s2 * (1.f / 128.f);
    float rstdN = rsqrtf(ss2 * (1.f / 128.f) - meanN * meanN + 1e-6f);
    float ov[8];
#pragma unroll
    for (int j = 0; j < 8; ++j) {
        float nn = (nv[j] - meanN) * rstdN * gn[j] + bn[j];
        float ll = (lv[j] - meanL) * rstdL * gl[j] + bl[j];
        float o = nn + ll;
        ov[j] = o > 0.f ? o : 0.f;
    }
    float4* op = (float4*)(out + (size_t)p * INC + c0);
    op[0] = ((float4*)ov)[0];
    op[1] = ((float4*)ov)[1];
}

// ---------------- cooperative single-dispatch kernel ------------------------
__global__ __launch_bounds__(256, 3) void k_all(
        const float* __restrict__ F, const float* __restrict__ w_pre,
        const float* __restrict__ w_conv, const int* __restrict__ nbr_idx,
        const int* __restrict__ coords, const float* __restrict__ counts_v,
        const float* __restrict__ w_pos, const float* __restrict__ alpha,
        const float* __restrict__ g_pre, const float* __restrict__ b_pre,
        const float* __restrict__ g_local, const float* __restrict__ b_local,
        const float* __restrict__ g_norm, const float* __restrict__ b_norm,
        __hip_bfloat16* __restrict__ Wp, __hip_bfloat16* __restrict__ Wpre,
        __hip_bfloat16* __restrict__ F_input, float* __restrict__ loc,
        float* __restrict__ loc2, int* __restrict__ cnt, int* __restrict__ dst,
        int* __restrict__ src, unsigned char* __restrict__ flg,
        int* __restrict__ ndl, float* __restrict__ out) {
    __shared__ SharedBlk sh;
    cg::grid_group gg = cg::this_grid();
    const int nb = gridDim.x;

    // phase -1: zero counters
    if (blockIdx.x == 0 && threadIdx.x < 32) cnt[threadIdx.x] = 0;
    gg.sync();

    // phase 0: prep + scan
    for (int t = blockIdx.x; t < PREP_BLOCKS + SCAN_BLOCKS; t += nb) {
        if (t < PREP_BLOCKS) do_prep(t, w_pre, w_conv, Wp, Wpre);
        else do_scan(t - PREP_BLOCKS, &sh, nbr_idx, counts_v, cnt, dst, src, flg, ndl, loc2);
        __syncthreads();
    }
    gg.sync();

    // phase 1: gemm + pairs
    load_params(&sh, g_pre, b_pre, g_local, b_local, g_norm, b_norm);
    __syncthreads();
    for (int t = blockIdx.x; t < MT64 + PAIRB; t += nb) {
        if (t < MT64) do_gemm(t, &sh, F, Wpre, Wp, flg, F_input, loc, out);
        else do_pairs(t - MT64, &sh, F, Wp, cnt, dst, src, loc2);
        __syncthreads();
    }
    gg.sync();

    // phase 2: final
    const int nd = cnt[26];
    const int nt = (nd + 15) >> 4;
    for (int t = blockIdx.x; t < nt; t += nb)
        do_final(t, nd, F_input, loc, loc2, nbr_idx, coords, counts_v,
                 w_pos, alpha, g_local, b_local, g_norm, b_norm, ndl, out);
}

// ---------------- fallback kernels (4-dispatch path) ------------------------
__global__ __launch_bounds__(256) void k_front_fb(
        const float* __restrict__ w_pre, const float* __restrict__ w_conv,
        __hip_bfloat16* __restrict__ Wp, __hip_bfloat16* __restrict__ Wpre,
        const int* __restrict__ nbr_idx, const float* __restrict__ counts_v,
        int* __restrict__ cnt, int* __restrict__ dst, int* __restrict__ src,
        unsigned char* __restrict__ flg, int* __restrict__ ndl,
        float* __restrict__ loc2) {
    __shared__ SharedBlk sh;
    if (blockIdx.x < PREP_BLOCKS) { do_prep(blockIdx.x, w_pre, w_conv, Wp, Wpre); return; }
    do_scan(blockIdx.x - PREP_BLOCKS, &sh, nbr_idx, counts_v, cnt, dst, src, flg, ndl, loc2);
}

__global__ __launch_bounds__(256, 3) void k_main_fb(
        const float* __restrict__ F, const __hip_bfloat16* __restrict__ Wpre,
        const __hip_bfloat16* __restrict__ Wp, const unsigned char* __restrict__ flg,
        const float* __restrict__ g_pre, const float* __restrict__ b_pre,
        const float* __restrict__ g_local, const float* __restrict__ b_local,
        const float* __restrict__ g_norm, const float* __restrict__ b_norm,
        const int* __restrict__ cnt, const int* __restrict__ dst,
        const int* __restrict__ src,
        __hip_bfloat16* __restrict__ F_input, float* __restrict__ loc,
        float* __restrict__ loc2, float* __restrict__ outp) {
    __shared__ SharedBlk sh;
    if (blockIdx.x >= MT64) { do_pairs(blockIdx.x - MT64, &sh, F, Wp, cnt, dst, src, loc2); return; }
    load_params(&sh, g_pre, b_pre, g_local, b_local, g_norm, b_norm);
    __syncthreads();
    do_gemm(blockIdx.x, &sh, F, Wpre, Wp, flg, F_input, loc, outp);
}

__global__ __launch_bounds__(256) void k_final_fb(
        const __hip_bfloat16* __restrict__ F_input, const float* __restrict__ loc,
        const float* __restrict__ loc2,
        const int* __restrict__ nbr_idx, const int* __restrict__ coords,
        const float* __restrict__ counts_v,
        const float* __restrict__ w_pos, const float* __restrict__ alpha,
        const float* __restrict__ g_local, const float* __restrict__ b_local,
        const float* __restrict__ g_norm, const float* __restrict__ b_norm,
        const int* __restrict__ cnt, const int* __restrict__ ndl,
        float* __restrict__ out) {
    const int nd = cnt[26];
    const int nt = (nd + 15) >> 4;
    for (int t = blockIdx.x; t < nt; t += gridDim.x)
        do_final(t, nd, F_input, loc, loc2, nbr_idx, coords, counts_v,
                 w_pos, alpha, g_local, b_local, g_norm, b_norm, ndl, out);
}

// ---------------- host launcher ---------------------------------------------
extern "C" void kernel_launch(void* const* d_in, const int* in_sizes, int n_in,
                              void* d_out, int out_size, void* d_ws, size_t ws_size,
                              hipStream_t stream) {
    (void)in_sizes; (void)n_in; (void)out_size; (void)ws_size;
    const float* F        = (const float*)d_in[0];
    const int*   coords   = (const int*)d_in[1];
    const int*   nbr      = (const int*)d_in[2];
    const float* counts_v = (const float*)d_in[4];
    const float* alpha    = (const float*)d_in[6];
    const float* w_pos    = (const float*)d_in[7];
    const float* w_pre    = (const float*)d_in[8];
    const float* g_pre    = (const float*)d_in[9];
    const float* b_pre    = (const float*)d_in[10];
    const float* w_conv   = (const float*)d_in[11];
    const float* g_local  = (const float*)d_in[12];
    const float* b_local  = (const float*)d_in[13];
    const float* g_norm   = (const float*)d_in[14];
    const float* b_norm   = (const float*)d_in[15];
    float* out = (float*)d_out;

    char* ws = (char*)d_ws;
    __hip_bfloat16* Wp      = (__hip_bfloat16*)(ws + OFF_WP);
    __hip_bfloat16* Wpre    = (__hip_bfloat16*)(ws + OFF_WPRE);
    __hip_bfloat16* F_input = (__hip_bfloat16*)(ws + OFF_FIN);
    float*          loc     = (float*)(ws + OFF_LOC);
    float*          loc2    = (float*)(ws + OFF_LOC2);
    int*            cnt     = (int*)(ws + OFF_CNT);
    int*            dstb    = (int*)(ws + OFF_DST);
    int*            srcb    = (int*)(ws + OFF_SRC);
    unsigned char*  flg     = (unsigned char*)(ws + OFF_FLG);
    int*            ndl     = (int*)(ws + OFF_NDL);

    // one-time: cooperative grid size from occupancy (0 => coop unusable)
    static int coop_grid = -1;
    if (coop_grid < 0) {
        int nbk = 0;
        hipError_t e = hipOccupancyMaxActiveBlocksPerMultiprocessor(&nbk, k_all, 256, 0);
        if (e != hipSuccess || nbk < 1) { coop_grid = 0; (void)hipGetLastError(); }
        else { if (nbk > 3) nbk = 3; coop_grid = nbk * 256; }
    }

    bool done = false;
    if (coop_grid > 0) {
        void* args[] = { (void*)&F, (void*)&w_pre, (void*)&w_conv, (void*)&nbr,
                         (void*)&coords, (void*)&counts_v, (void*)&w_pos, (void*)&alpha,
                         (void*)&g_pre, (void*)&b_pre, (void*)&g_local, (void*)&b_local,
                         (void*)&g_norm, (void*)&b_norm, (void*)&Wp, (void*)&Wpre,
                         (void*)&F_input, (void*)&loc, (void*)&loc2, (void*)&cnt,
                         (void*)&dstb, (void*)&srcb, (void*)&flg, (void*)&ndl, (void*)&out };
        hipError_t e = hipLaunchCooperativeKernel((const void*)k_all, dim3(coop_grid),
                                                  dim3(256), args, 0, stream);
        if (e == hipSuccess) done = true;
        else { coop_grid = 0; (void)hipGetLastError(); }
    }

    if (!done) {
        hipMemsetAsync(cnt, 0, SZ_CNT, stream);
        k_front_fb<<<PREP_BLOCKS + SCAN_BLOCKS, 256, 0, stream>>>(
            w_pre, w_conv, Wp, Wpre, nbr, counts_v, cnt, dstb, srcb, flg, ndl, loc2);
        k_main_fb<<<MT64 + PAIRB, 256, 0, stream>>>(
            F, Wpre, Wp, flg, g_pre, b_pre, g_local, b_local, g_norm, b_norm,
            cnt, dstb, srcb, F_input, loc, loc2, out);
        k_final_fb<<<1024, 256, 0, stream>>>(F_input, loc, loc2, nbr, coords, counts_v,
                                             w_pos, alpha, g_local, b_local, g_norm, b_norm,
                                             cnt, ndl, out);
    }
}

// Round 10
// 209.338 us; speedup vs baseline: 1.5151x; 1.3304x over previous
//
#include <hip/hip_runtime.h>
#include <hip/hip_bf16.h>
#include <stdint.h>

#define N_PTS 100000
#define INC 128
#define NSLOT 27
#define CAPP 8192                 // pairs per slot-bucket (expected ~620)

typedef float f32x4 __attribute__((ext_vector_type(4)));
typedef short bf16x8 __attribute__((ext_vector_type(8)));

// ---------------- workspace layout --------------------------------------
static const size_t OFF_WP   = 0;                                        // 27 slots frag-packed bf16
static const size_t SZ_WP    = (size_t)NSLOT * INC * INC * 2;
static const size_t OFF_WPRE = (OFF_WP + SZ_WP + 255) & ~(size_t)255;    // w_pre frag-packed bf16
static const size_t SZ_WPRE  = (size_t)INC * INC * 2;
static const size_t OFF_FIN  = (OFF_WPRE + SZ_WPRE + 255) & ~(size_t)255; // F_input bf16
static const size_t SZ_FIN   = (size_t)N_PTS * INC * 2;
static const size_t OFF_LOC  = (OFF_FIN + SZ_FIN + 255) & ~(size_t)255;   // self-conv f32 (by gemm)
static const size_t SZ_LOC   = (size_t)N_PTS * INC * 4;
static const size_t OFF_LOC2 = (OFF_LOC + SZ_LOC + 255) & ~(size_t)255;   // neighbor-conv f32 (atomics)
static const size_t SZ_LOC2  = (size_t)N_PTS * INC * 4;
static const size_t OFF_CNT  = (OFF_LOC2 + SZ_LOC2 + 255) & ~(size_t)255; // 26 bucket counters + [26]=ndl
static const size_t SZ_CNT   = 128;
static const size_t OFF_DST  = (OFF_CNT + SZ_CNT + 255) & ~(size_t)255;
static const size_t SZ_DST   = (size_t)26 * CAPP * 4;
static const size_t OFF_SRC  = (OFF_DST + SZ_DST + 255) & ~(size_t)255;
static const size_t SZ_SRC   = (size_t)26 * CAPP * 4;
static const size_t OFF_FLG  = (OFF_SRC + SZ_SRC + 255) & ~(size_t)255;   // per-point flags u8
static const size_t SZ_FLG   = (size_t)N_PTS;
static const size_t OFF_NDL  = (OFF_FLG + SZ_FLG + 255) & ~(size_t)255;   // needs-final point list
static const size_t SZ_NDL   = (size_t)N_PTS * 4;                          // total ~131 MB

#define PREP_BLOCKS 1792
#define SCAN_BLOCKS 391
#define MT64 1563                 // gemm tasks
#define PAIRB 256                 // pairs tasks

__device__ __forceinline__ float compute_pos3(float w0, float w1, float w2, float a,
                                              float cx, float cy, float cz) {
    return (cx * w0 + cy * w1 + cz * w2) * a;
}

__device__ __forceinline__ bf16x8 ld_cvt8(const float* __restrict__ p) {
    const float4 u = *(const float4*)p;
    const float4 v = *(const float4*)(p + 4);
    bf16x8 r;
    __hip_bfloat16* h = (__hip_bfloat16*)&r;
    h[0] = __float2bfloat16(u.x); h[1] = __float2bfloat16(u.y);
    h[2] = __float2bfloat16(u.z); h[3] = __float2bfloat16(u.w);
    h[4] = __float2bfloat16(v.x); h[5] = __float2bfloat16(v.y);
    h[6] = __float2bfloat16(v.z); h[7] = __float2bfloat16(v.w);
    return r;
}

// ---------------- K_front: weight pack + block-staged ballot scan -----------
// Scan (verified in R9's coop run): per-wave ballots -> LDS masks -> 26
// PARALLEL block-level global atomics (392 per address grid-wide) -> direct
// scatter. No per-thread LDS atomic contention (R7) and no per-wave global
// atomics (R8's 139us disaster). Own kernel => own register budget (R9 lesson:
// fused union allocation spilled ~230 MB of scratch).
__global__ __launch_bounds__(256) void k_front(
        const float* __restrict__ w_pre, const float* __restrict__ w_conv,
        __hip_bfloat16* __restrict__ Wp, __hip_bfloat16* __restrict__ Wpre,
        const int* __restrict__ nbr_idx, const float* __restrict__ counts_v,
        int* __restrict__ cnt, int* __restrict__ dst, int* __restrict__ src,
        unsigned char* __restrict__ flg, int* __restrict__ ndl,
        float* __restrict__ loc2) {
    __shared__ unsigned long long s_msk[4][26];
    __shared__ unsigned long long s_ndm[4];
    __shared__ int s_base[26];
    __shared__ int s_nbase;

    const int tid = threadIdx.x;

    if (blockIdx.x < PREP_BLOCKS) {
        int i = blockIdx.x * 256 + tid;
        if (i < 16384) {                        // w_pre: B[n=d][k=c] = w_pre[d*128+c]
            int d = i >> 7, c = i & 127;
            int j = ((c >> 5) << 12) | ((d >> 4) << 9)
                  | (((((c >> 3) & 3) << 4) + (d & 15)) << 3) | (c & 7);
            Wpre[j] = __float2bfloat16(w_pre[i]);
        } else if (i < 16384 + NSLOT * 16384) { // w_conv: B[n=d][k=c] = w_conv[slot][c][d]
            int t = i - 16384;
            int slot = t >> 14, rem = t & 16383;
            int c = rem >> 7, d = rem & 127;
            int j = (slot << 14) | ((c >> 5) << 12) | ((d >> 4) << 9)
                  | (((((c >> 3) & 3) << 4) + (d & 15)) << 3) | (c & 7);
            Wp[j] = __float2bfloat16(w_conv[t]);
        }
        return;
    }

    const int w = tid >> 6, lane = tid & 63;
    const int p = (blockIdx.x - PREP_BLOCKS) * 256 + tid;
    const bool vp = p < N_PTS;

    float cv = vp ? counts_v[p] : 0.f;
    bool multi = cv > 1.5f;

    const int* nb = nbr_idx + (size_t)p * NSLOT;
    int nbr_r[NSLOT];
#pragma unroll
    for (int k = 0; k < NSLOT; ++k) nbr_r[k] = vp ? nb[k] : N_PTS;

    bool hn = false;
#pragma unroll
    for (int k = 0; k < NSLOT; ++k) {
        if (k == 13) continue;
        bool valid = nbr_r[k] < N_PTS;
        hn = hn || valid;
        unsigned long long msk = __ballot(valid);
        int b = k < 13 ? k : k - 1;
        if (lane == 0) s_msk[w][b] = msk;
    }
    bool ndv = vp && (hn || multi);
    unsigned long long ndm = __ballot(ndv);
    if (lane == 0) s_ndm[w] = ndm;
    __syncthreads();

    if (tid < 26) {
        int tot = 0;
#pragma unroll
        for (int ww = 0; ww < 4; ++ww) tot += __popcll(s_msk[ww][tid]);
        s_base[tid] = tot ? atomicAdd(&cnt[tid], tot) : 0;
    } else if (tid == 32) {
        int tot = 0;
#pragma unroll
        for (int ww = 0; ww < 4; ++ww) tot += __popcll(s_ndm[ww]);
        s_nbase = tot ? atomicAdd(&cnt[26], tot) : 0;
    }
    __syncthreads();

    // scatter buckets
#pragma unroll
    for (int k = 0; k < NSLOT; ++k) {
        if (k == 13) continue;
        int b = k < 13 ? k : k - 1;
        if (nbr_r[k] < N_PTS) {
            unsigned long long msk = s_msk[w][b];
            int pre = 0;
            for (int ww = 0; ww < w; ++ww) pre += __popcll(s_msk[ww][b]);
            int gi = s_base[b] + pre + __popcll(msk & ((1ull << lane) - 1ull));
            if (gi < CAPP) { dst[b * CAPP + gi] = p; src[b * CAPP + gi] = nbr_r[k]; }
        }
    }

    if (vp) flg[p] = (unsigned char)(ndv ? 1 : 0);
    if (ndv) {
        float4* row = (float4*)(loc2 + (size_t)p * INC);
#pragma unroll
        for (int i = 0; i < INC / 4; ++i) row[i] = make_float4(0.f, 0.f, 0.f, 0.f);
        unsigned long long m2 = s_ndm[w];
        int pre = 0;
        for (int ww = 0; ww < w; ++ww) pre += __popcll(s_ndm[ww]);
        ndl[s_nbase + pre + __popcll(m2 & ((1ull << lane) - 1ull))] = p;
    }
}

// ---------------- K_main: FUSED gemm-region + pairs-region ------------------
// blocks [0, MT64): merged pre_mix + self-conv GEMM (phase-split pipelined
// MFMA loop) with fused final for done rows. blocks [MT64, ..): neighbor
// pairs into loc2 -- co-scheduled, latency hides under gemm compute.
__global__ __launch_bounds__(256, 3) void k_main(
        const float* __restrict__ F, const __hip_bfloat16* __restrict__ Wpre,
        const __hip_bfloat16* __restrict__ Wp, const unsigned char* __restrict__ flg,
        const float* __restrict__ g_pre, const float* __restrict__ b_pre,
        const float* __restrict__ g_local, const float* __restrict__ b_local,
        const float* __restrict__ g_norm, const float* __restrict__ b_norm,
        const int* __restrict__ cnt, const int* __restrict__ dst,
        const int* __restrict__ src,
        __hip_bfloat16* __restrict__ F_input, float* __restrict__ loc,
        float* __restrict__ loc2, float* __restrict__ outp) {
    __shared__ __hip_bfloat16 s_bf[4][16 * 136];   // per-wave F_input staging (gemm)
    __shared__ float s_gp[INC], s_bp[INC], s_gl[INC], s_bl[INC], s_gn[INC], s_bn[INC];
    __shared__ int s_wre[27], s_cntb[26];          // pairs region

    const int tid = threadIdx.x, w = tid >> 6, lane = tid & 63;
    const int q = lane >> 4, l15 = lane & 15;

    if (blockIdx.x >= MT64) {
        // ================= pairs region =================
        const int pb = blockIdx.x - MT64;
        if (tid < 26) { int v = cnt[tid]; if (v > CAPP) v = CAPP; s_cntb[tid] = v; }
        __syncthreads();
        if (tid == 0) {
            int accw = 0; s_wre[0] = 0;
            for (int b = 0; b < 26; ++b) { accw += (s_cntb[b] + 15) >> 4; s_wre[b + 1] = accw; }
        }
        __syncthreads();
        const int W = s_wre[26];
#pragma unroll 1
        for (int wvi = pb * 4 + w; wvi < W; wvi += PAIRB * 4) {
            int b = 0;
            while (wvi >= s_wre[b + 1]) ++b;       // wave-uniform
            int base = (wvi - s_wre[b]) << 4;
            int nB = s_cntb[b];
            int slot = b < 13 ? b : b + 1;
            const int* srcb = src + b * CAPP;
            const int* dstb = dst + b * CAPP;
            int mrow = (base + l15 < nB) ? srcb[base + l15] : 0;
            const bf16x8* Bp = (const bf16x8*)Wp + (size_t)slot * 2048;

            f32x4 acc[8];
#pragma unroll
            for (int j = 0; j < 8; ++j) acc[j] = (f32x4){0.f, 0.f, 0.f, 0.f};
#pragma unroll
            for (int ks = 0; ks < 4; ++ks) {
                bf16x8 a2 = ld_cvt8(F + (size_t)mrow * INC + ks * 32 + q * 8);
#pragma unroll
                for (int j = 0; j < 8; ++j)
                    acc[j] = __builtin_amdgcn_mfma_f32_16x16x32_bf16(
                        a2, Bp[(ks * 8 + j) * 64 + lane], acc[j], 0, 0, 0);
            }
#pragma unroll
            for (int r = 0; r < 4; ++r) {
                int m = (q << 2) + r;
                int ri = base + m;
                if (ri < nB) {
                    int d = dstb[ri];
                    float* lp = loc2 + (size_t)d * INC + l15;
#pragma unroll
                    for (int j = 0; j < 8; ++j) atomicAdd(lp + (j << 4), acc[j][r]);
                }
            }
        }
        return;
    }

    // ================= gemm region =================
    const int p0 = blockIdx.x * 64;

    if (tid < INC) {
        s_gp[tid] = g_pre[tid];   s_bp[tid] = b_pre[tid];
        s_gl[tid] = g_local[tid]; s_bl[tid] = b_local[tid];
        s_gn[tid] = g_norm[tid];  s_bn[tid] = b_norm[tid];
    }
    __syncthreads();

    int grow = p0 + (w << 4) + l15;
    if (grow >= N_PTS) grow = N_PTS - 1;      // clamp; stores guarded

    const float* A = F + (size_t)grow * INC + q * 8;

    unsigned int fe = *(const unsigned int*)(flg + p0 + (w << 4) + (q << 2));
    unsigned char fs0 = flg[p0 + (w << 4) + q];
    unsigned char fs1 = flg[p0 + (w << 4) + 4 + q];
    unsigned char fs2 = flg[p0 + (w << 4) + 8 + q];
    unsigned char fs3 = flg[p0 + (w << 4) + 12 + q];

    bf16x8 a[4];
#pragma unroll
    for (int ks = 0; ks < 4; ++ks) a[ks] = ld_cvt8(A + ks * 32);

    const bf16x8* BP = (const bf16x8*)Wpre;
    const bf16x8* BL = (const bf16x8*)Wp + (size_t)13 * 2048;
    f32x4 accP[8], accL[8];
#pragma unroll
    for (int j = 0; j < 8; ++j) {
        accP[j] = (f32x4){0.f, 0.f, 0.f, 0.f};
        accL[j] = (f32x4){0.f, 0.f, 0.f, 0.f};
    }
    bf16x8 bP[8], bL[8];
#pragma unroll
    for (int j = 0; j < 8; ++j) bP[j] = BP[j * 64 + lane];
#pragma unroll
    for (int ks = 0; ks < 4; ++ks) {
#pragma unroll
        for (int j = 0; j < 8; ++j) bL[j] = BL[(ks * 8 + j) * 64 + lane];
#pragma unroll
        for (int j = 0; j < 8; ++j)
            accP[j] = __builtin_amdgcn_mfma_f32_16x16x32_bf16(a[ks], bP[j], accP[j], 0, 0, 0);
        if (ks < 3) {
#pragma unroll
            for (int j = 0; j < 8; ++j) bP[j] = BP[((ks + 1) * 8 + j) * 64 + lane];
        }
#pragma unroll
        for (int j = 0; j < 8; ++j)
            accL[j] = __builtin_amdgcn_mfma_f32_16x16x32_bf16(a[ks], bL[j], accL[j], 0, 0, 0);
    }

    __hip_bfloat16* sb = s_bf[w];
#pragma unroll
    for (int r = 0; r < 4; ++r) {
        int ri = (q << 2) + r;
        int p = p0 + (w << 4) + ri;
        int fl = (p < N_PTS) ? (int)((fe >> (r * 8)) & 1) : 1;

        float s = 0.f, ss = 0.f;
#pragma unroll
        for (int j = 0; j < 8; ++j) { float v = accP[j][r]; s += v; ss += v * v; }
#pragma unroll
        for (int m = 1; m < 16; m <<= 1) { s += __shfl_xor(s, m); ss += __shfl_xor(ss, m); }
        float mean = s * (1.f / 128.f);
        float rstd = rsqrtf(ss * (1.f / 128.f) - mean * mean + 1e-6f);

        float fj[8], sN = 0.f, ssN = 0.f, sL = 0.f, ssL = 0.f;
#pragma unroll
        for (int j = 0; j < 8; ++j) {
            int c = (j << 4) + l15;
            float fi = (accP[j][r] - mean) * rstd * s_gp[c] + s_bp[c];
            __hip_bfloat16 fb = __float2bfloat16(fi);
            sb[ri * 136 + c] = fb;
            float f = __bfloat162float(fb);
            fj[j] = f; sN += f; ssN += f * f;
            float v = accL[j][r]; sL += v; ssL += v * v;
        }
#pragma unroll
        for (int m = 1; m < 16; m <<= 1) {
            sN += __shfl_xor(sN, m); ssN += __shfl_xor(ssN, m);
            sL += __shfl_xor(sL, m); ssL += __shfl_xor(ssL, m);
        }
        float meanN = sN * (1.f / 128.f);
        float rstdN = rsqrtf(ssN * (1.f / 128.f) - meanN * meanN + 1e-6f);
        float meanL = sL * (1.f / 128.f);
        float rstdL = rsqrtf(ssL * (1.f / 128.f) - meanL * meanL + 1e-6f);

        if (p < N_PTS) {
            float* dp = fl ? (loc + (size_t)p * INC) : (outp + (size_t)p * INC);
#pragma unroll
            for (int j = 0; j < 8; ++j) {
                int c = (j << 4) + l15;
                float lvj = accL[j][r];
                float nn = (fj[j] - meanN) * rstdN * s_gn[c] + s_bn[c];
                float ll = (lvj - meanL) * rstdL * s_gl[c] + s_bl[c];
                float o = nn + ll; o = o > 0.f ? o : 0.f;
                dp[c] = fl ? lvj : o;
            }
        }
    }

    unsigned char fsv[4] = {fs0, fs1, fs2, fs3};
#pragma unroll
    for (int t = 0; t < 4; ++t) {
        int row = (t << 2) + q;
        int p = p0 + (w << 4) + row;
        if (p < N_PTS && (fsv[t] & 1)) {
            bf16x8 v = *(const bf16x8*)&sb[row * 136 + l15 * 8];
            *(bf16x8*)(F_input + (size_t)p * INC + l15 * 8) = v;
        }
    }
}

// ---------------- K_final: sparse pass; vox via cellmate GATHER -------------
__global__ __launch_bounds__(256) void k_final(
        const __hip_bfloat16* __restrict__ F_input, const float* __restrict__ loc,
        const float* __restrict__ loc2,
        const int* __restrict__ nbr_idx, const int* __restrict__ coords,
        const float* __restrict__ counts_v,
        const float* __restrict__ w_pos, const float* __restrict__ alpha,
        const float* __restrict__ g_local, const float* __restrict__ b_local,
        const float* __restrict__ g_norm, const float* __restrict__ b_norm,
        const int* __restrict__ cnt, const int* __restrict__ ndl,
        float* __restrict__ out) {
    const int tid = threadIdx.x, g = tid >> 4, l15 = tid & 15;
    const int c0 = l15 * 8;
    const int nd = cnt[26];
    if (blockIdx.x * 16 >= nd) return;

    float wpv[24], pa[8], gl[8], bl[8], gn[8], bn[8];
#pragma unroll
    for (int t = 0; t < 6; ++t) ((float4*)wpv)[t] = ((const float4*)(w_pos + c0 * 3))[t];
#pragma unroll
    for (int t = 0; t < 2; ++t) {
        ((float4*)pa)[t] = ((const float4*)(alpha   + c0))[t];
        ((float4*)gl)[t] = ((const float4*)(g_local + c0))[t];
        ((float4*)bl)[t] = ((const float4*)(b_local + c0))[t];
        ((float4*)gn)[t] = ((const float4*)(g_norm  + c0))[t];
        ((float4*)bn)[t] = ((const float4*)(b_norm  + c0))[t];
    }

    for (int base = blockIdx.x * 16; base < nd; base += gridDim.x * 16) {
        int idx = base + g;
        if (idx >= nd) continue;
        int p = ndl[idx];

        float lv[8], s = 0.f, ss = 0.f;
        float4 la0 = *(const float4*)(loc  + (size_t)p * INC + c0);
        float4 la1 = *(const float4*)(loc  + (size_t)p * INC + c0 + 4);
        float4 lb0 = *(const float4*)(loc2 + (size_t)p * INC + c0);
        float4 lb1 = *(const float4*)(loc2 + (size_t)p * INC + c0 + 4);
        lv[0] = la0.x + lb0.x; lv[1] = la0.y + lb0.y;
        lv[2] = la0.z + lb0.z; lv[3] = la0.w + lb0.w;
        lv[4] = la1.x + lb1.x; lv[5] = la1.y + lb1.y;
        lv[6] = la1.z + lb1.z; lv[7] = la1.w + lb1.w;
#pragma unroll
        for (int j = 0; j < 8; ++j) { s += lv[j]; ss += lv[j] * lv[j]; }
#pragma unroll
        for (int m = 1; m < 16; m <<= 1) { s += __shfl_xor(s, m); ss += __shfl_xor(ss, m); }
        float meanL = s * (1.f / 128.f);
        float rstdL = rsqrtf(ss * (1.f / 128.f) - meanL * meanL + 1e-6f);

        float cv = counts_v[p];
        bool multi = cv > 1.5f;
        int ix = coords[p * 3 + 0], iy = coords[p * 3 + 1], iz = coords[p * 3 + 2];
        float cx = (float)ix, cy = (float)iy, cz = (float)iz;

        bf16x8 fbv = *(const bf16x8*)(F_input + (size_t)p * INC + c0);

        float psO[8], snO[8], csO[8], fO[8];
#pragma unroll
        for (int j = 0; j < 8; ++j) {
            fO[j] = __bfloat162float(((__hip_bfloat16*)&fbv)[j]);
            psO[j] = compute_pos3(wpv[j * 3], wpv[j * 3 + 1], wpv[j * 3 + 2], pa[j], cx, cy, cz);
            snO[j] = __sinf(psO[j]); csO[j] = __cosf(psO[j]);
        }

        float v0[8], v1[8], v2[8];
        if (multi) {
            float invc = 1.f / cv;
            int ox = (ix & 1) ? -1 : 1, oy = (iy & 1) ? -1 : 1, oz = (iz & 1) ? -1 : 1;
            const int* nb = nbr_idx + (size_t)p * NSLOT;
            unsigned vmask = 1u;
            bf16x8 fmv8[8];
            fmv8[0] = fbv;
#pragma unroll
            for (int e = 1; e < 8; ++e) {
                int dx = (e & 4) ? ox : 0, dy = (e & 2) ? oy : 0, dz = (e & 1) ? oz : 0;
                int m = nb[(dx + 1) * 9 + (dy + 1) * 3 + (dz + 1)];
                bool ok = m < N_PTS;
                if (ok) vmask |= (1u << e);
                int mc = ok ? m : p;
                fmv8[e] = *(const bf16x8*)(F_input + (size_t)mc * INC + c0);
            }
#pragma unroll
            for (int j = 0; j < 8; ++j) { v0[j] = 0.f; v1[j] = 0.f; v2[j] = 0.f; }
#pragma unroll
            for (int e = 0; e < 8; ++e) {
                float wt = ((vmask >> e) & 1u) ? 1.f : 0.f;
                int dx = (e & 4) ? ox : 0, dy = (e & 2) ? oy : 0, dz = (e & 1) ? oz : 0;
                float mx = cx + (float)dx, my = cy + (float)dy, mz = cz + (float)dz;
#pragma unroll
                for (int j = 0; j < 8; ++j) {
                    float fm = wt * __bfloat162float(((__hip_bfloat16*)&fmv8[e])[j]);
                    float ps = compute_pos3(wpv[j * 3], wpv[j * 3 + 1], wpv[j * 3 + 2], pa[j],
                                            mx, my, mz);
                    v0[j] += fm * __cosf(ps);
                    v1[j] += fm * __sinf(ps);
                    v2[j] += fm * ps;
                }
            }
#pragma unroll
            for (int j = 0; j < 8; ++j) { v0[j] *= invc; v1[j] *= invc; v2[j] *= invc; }
        } else {
#pragma unroll
            for (int j = 0; j < 8; ++j) {
                v0[j] = fO[j] * csO[j]; v1[j] = fO[j] * snO[j]; v2[j] = fO[j] * psO[j];
            }
        }

        float nv[8], s2 = 0.f, ss2 = 0.f;
#pragma unroll
        for (int j = 0; j < 8; ++j) {
            float nw = v0[j] * csO[j] + v1[j] * snO[j] + v2[j] - fO[j] * psO[j];
            nv[j] = nw; s2 += nw; ss2 += nw * nw;
        }
#pragma unroll
        for (int m = 1; m < 16; m <<= 1) { s2 += __shfl_xor(s2, m); ss2 += __shfl_xor(ss2, m); }
        float meanN = s2 * (1.f / 128.f);
        float rstdN = rsqrtf(ss2 * (1.f / 128.f) - meanN * meanN + 1e-6f);
        float ov[8];
#pragma unroll
        for (int j = 0; j < 8; ++j) {
            float nn = (nv[j] - meanN) * rstdN * gn[j] + bn[j];
            float ll = (lv[j] - meanL) * rstdL * gl[j] + bl[j];
            float o = nn + ll;
            ov[j] = o > 0.f ? o : 0.f;
        }
        float4* op = (float4*)(out + (size_t)p * INC + c0);
        op[0] = ((float4*)ov)[0];
        op[1] = ((float4*)ov)[1];
    }
}

// ---------------- host launcher ---------------------------------------------
extern "C" void kernel_launch(void* const* d_in, const int* in_sizes, int n_in,
                              void* d_out, int out_size, void* d_ws, size_t ws_size,
                              hipStream_t stream) {
    (void)in_sizes; (void)n_in; (void)out_size; (void)ws_size;
    const float* F        = (const float*)d_in[0];
    const int*   coords   = (const int*)d_in[1];
    const int*   nbr      = (const int*)d_in[2];
    const float* counts_v = (const float*)d_in[4];
    const float* alpha    = (const float*)d_in[6];
    const float* w_pos    = (const float*)d_in[7];
    const float* w_pre    = (const float*)d_in[8];
    const float* g_pre    = (const float*)d_in[9];
    const float* b_pre    = (const float*)d_in[10];
    const float* w_conv   = (const float*)d_in[11];
    const float* g_local  = (const float*)d_in[12];
    const float* b_local  = (const float*)d_in[13];
    const float* g_norm   = (const float*)d_in[14];
    const float* b_norm   = (const float*)d_in[15];
    float* out = (float*)d_out;

    char* ws = (char*)d_ws;
    __hip_bfloat16* Wp      = (__hip_bfloat16*)(ws + OFF_WP);
    __hip_bfloat16* Wpre    = (__hip_bfloat16*)(ws + OFF_WPRE);
    __hip_bfloat16* F_input = (__hip_bfloat16*)(ws + OFF_FIN);
    float*          loc     = (float*)(ws + OFF_LOC);
    float*          loc2    = (float*)(ws + OFF_LOC2);
    int*            cnt     = (int*)(ws + OFF_CNT);
    int*            dstb    = (int*)(ws + OFF_DST);
    int*            srcb    = (int*)(ws + OFF_SRC);
    unsigned char*  flg     = (unsigned char*)(ws + OFF_FLG);
    int*            ndl     = (int*)(ws + OFF_NDL);

    hipMemsetAsync(cnt, 0, SZ_CNT, stream);
    k_front<<<PREP_BLOCKS + SCAN_BLOCKS, 256, 0, stream>>>(
        w_pre, w_conv, Wp, Wpre, nbr, counts_v, cnt, dstb, srcb, flg, ndl, loc2);
    k_main<<<MT64 + PAIRB, 256, 0, stream>>>(
        F, Wpre, Wp, flg, g_pre, b_pre, g_local, b_local, g_norm, b_norm,
        cnt, dstb, srcb, F_input, loc, loc2, out);
    k_final<<<1024, 256, 0, stream>>>(F_input, loc, loc2, nbr, coords, counts_v,
                                      w_pos, alpha, g_local, b_local, g_norm, b_norm,
                                      cnt, ndl, out);
}

// Round 11
// 201.458 us; speedup vs baseline: 1.5743x; 1.0391x over previous
//
#include <hip/hip_runtime.h>
#include <hip/hip_bf16.h>
#include <stdint.h>

#define N_PTS 100000
#define INC 128
#define NSLOT 27
#define CAPP 8192                 // pairs per slot-bucket (expected ~620)

typedef float f32x4 __attribute__((ext_vector_type(4)));
typedef short bf16x8 __attribute__((ext_vector_type(8)));

// ---------------- workspace layout --------------------------------------
static const size_t OFF_WP   = 0;                                        // 27 slots frag-packed bf16
static const size_t SZ_WP    = (size_t)NSLOT * INC * INC * 2;
static const size_t OFF_WPRE = (OFF_WP + SZ_WP + 255) & ~(size_t)255;    // w_pre frag-packed bf16
static const size_t SZ_WPRE  = (size_t)INC * INC * 2;
static const size_t OFF_FIN  = (OFF_WPRE + SZ_WPRE + 255) & ~(size_t)255; // F_input bf16
static const size_t SZ_FIN   = (size_t)N_PTS * INC * 2;
static const size_t OFF_LOC2 = (OFF_FIN + SZ_FIN + 255) & ~(size_t)255;   // conv accum f32 (atomics)
static const size_t SZ_LOC2  = (size_t)N_PTS * INC * 4;
static const size_t OFF_CNT  = (OFF_LOC2 + SZ_LOC2 + 255) & ~(size_t)255; // 26 bucket counters + [26]=ndl
static const size_t SZ_CNT   = 128;
static const size_t OFF_DST  = (OFF_CNT + SZ_CNT + 255) & ~(size_t)255;
static const size_t SZ_DST   = (size_t)26 * CAPP * 4;
static const size_t OFF_SRC  = (OFF_DST + SZ_DST + 255) & ~(size_t)255;
static const size_t SZ_SRC   = (size_t)26 * CAPP * 4;
static const size_t OFF_FLG  = (OFF_SRC + SZ_SRC + 255) & ~(size_t)255;   // per-point flags u8
static const size_t SZ_FLG   = (size_t)N_PTS;
static const size_t OFF_NDL  = (OFF_FLG + SZ_FLG + 255) & ~(size_t)255;   // needs-final point list
static const size_t SZ_NDL   = (size_t)N_PTS * 4;                          // total ~80 MB

#define PREP_BLOCKS 1792
#define SCAN_BLOCKS 391
#define MT64 1563                 // gemm tasks
#define PAIRB 256                 // pairs tasks

__device__ __forceinline__ float compute_pos3(float w0, float w1, float w2, float a,
                                              float cx, float cy, float cz) {
    return (cx * w0 + cy * w1 + cz * w2) * a;
}

__device__ __forceinline__ bf16x8 ld_cvt8(const float* __restrict__ p) {
    const float4 u = *(const float4*)p;
    const float4 v = *(const float4*)(p + 4);
    bf16x8 r;
    __hip_bfloat16* h = (__hip_bfloat16*)&r;
    h[0] = __float2bfloat16(u.x); h[1] = __float2bfloat16(u.y);
    h[2] = __float2bfloat16(u.z); h[3] = __float2bfloat16(u.w);
    h[4] = __float2bfloat16(v.x); h[5] = __float2bfloat16(v.y);
    h[6] = __float2bfloat16(v.z); h[7] = __float2bfloat16(v.w);
    return r;
}

// ---------------- K_front: weight pack + block-staged ballot scan -----------
// loc2 zeroing is now WAVE-COOPERATIVE: iterate the wave's nd-mask, all 64
// lanes zero each 512B row together (float2/lane) -- ~10 coalesced stores per
// wave instead of ~320 scattered 16B stores.
__global__ __launch_bounds__(256) void k_front(
        const float* __restrict__ w_pre, const float* __restrict__ w_conv,
        __hip_bfloat16* __restrict__ Wp, __hip_bfloat16* __restrict__ Wpre,
        const int* __restrict__ nbr_idx, const float* __restrict__ counts_v,
        int* __restrict__ cnt, int* __restrict__ dst, int* __restrict__ src,
        unsigned char* __restrict__ flg, int* __restrict__ ndl,
        float* __restrict__ loc2) {
    __shared__ unsigned long long s_msk[4][26];
    __shared__ unsigned long long s_ndm[4];
    __shared__ int s_base[26];
    __shared__ int s_nbase;

    const int tid = threadIdx.x;

    if (blockIdx.x < PREP_BLOCKS) {
        int i = blockIdx.x * 256 + tid;
        if (i < 16384) {                        // w_pre: B[n=d][k=c] = w_pre[d*128+c]
            int d = i >> 7, c = i & 127;
            int j = ((c >> 5) << 12) | ((d >> 4) << 9)
                  | (((((c >> 3) & 3) << 4) + (d & 15)) << 3) | (c & 7);
            Wpre[j] = __float2bfloat16(w_pre[i]);
        } else if (i < 16384 + NSLOT * 16384) { // w_conv: B[n=d][k=c] = w_conv[slot][c][d]
            int t = i - 16384;
            int slot = t >> 14, rem = t & 16383;
            int c = rem >> 7, d = rem & 127;
            int j = (slot << 14) | ((c >> 5) << 12) | ((d >> 4) << 9)
                  | (((((c >> 3) & 3) << 4) + (d & 15)) << 3) | (c & 7);
            Wp[j] = __float2bfloat16(w_conv[t]);
        }
        return;
    }

    const int w = tid >> 6, lane = tid & 63;
    const int p = (blockIdx.x - PREP_BLOCKS) * 256 + tid;
    const bool vp = p < N_PTS;

    float cv = vp ? counts_v[p] : 0.f;
    bool multi = cv > 1.5f;

    const int* nb = nbr_idx + (size_t)p * NSLOT;
    int nbr_r[NSLOT];
#pragma unroll
    for (int k = 0; k < NSLOT; ++k) nbr_r[k] = vp ? nb[k] : N_PTS;

    bool hn = false;
#pragma unroll
    for (int k = 0; k < NSLOT; ++k) {
        if (k == 13) continue;
        bool valid = nbr_r[k] < N_PTS;
        hn = hn || valid;
        unsigned long long msk = __ballot(valid);
        int b = k < 13 ? k : k - 1;
        if (lane == 0) s_msk[w][b] = msk;
    }
    bool ndv = vp && (hn || multi);
    unsigned long long ndm = __ballot(ndv);
    if (lane == 0) s_ndm[w] = ndm;
    __syncthreads();

    if (tid < 26) {
        int tot = 0;
#pragma unroll
        for (int ww = 0; ww < 4; ++ww) tot += __popcll(s_msk[ww][tid]);
        s_base[tid] = tot ? atomicAdd(&cnt[tid], tot) : 0;
    } else if (tid == 32) {
        int tot = 0;
#pragma unroll
        for (int ww = 0; ww < 4; ++ww) tot += __popcll(s_ndm[ww]);
        s_nbase = tot ? atomicAdd(&cnt[26], tot) : 0;
    }
    __syncthreads();

    // scatter buckets
#pragma unroll
    for (int k = 0; k < NSLOT; ++k) {
        if (k == 13) continue;
        int b = k < 13 ? k : k - 1;
        if (nbr_r[k] < N_PTS) {
            unsigned long long msk = s_msk[w][b];
            int pre = 0;
            for (int ww = 0; ww < w; ++ww) pre += __popcll(s_msk[ww][b]);
            int gi = s_base[b] + pre + __popcll(msk & ((1ull << lane) - 1ull));
            if (gi < CAPP) { dst[b * CAPP + gi] = p; src[b * CAPP + gi] = nbr_r[k]; }
        }
    }

    if (vp) flg[p] = (unsigned char)(ndv ? 1 : 0);
    unsigned long long m2 = s_ndm[w];
    if (ndv) {
        int pre = 0;
        for (int ww = 0; ww < w; ++ww) pre += __popcll(s_ndm[ww]);
        ndl[s_nbase + pre + __popcll(m2 & ((1ull << lane) - 1ull))] = p;
    }
    // wave-cooperative zero of loc2 rows (mask is wave-uniform)
    int wave_p0 = (blockIdx.x - PREP_BLOCKS) * 256 + (w << 6);
    unsigned long long mz = m2;
    while (mz) {
        int e = __ffsll((unsigned long long)mz) - 1;
        mz &= mz - 1;
        *(float2*)(loc2 + (size_t)(wave_p0 + e) * INC + (lane << 1)) = make_float2(0.f, 0.f);
    }
}

// ---------------- K_main: FUSED gemm-region + pairs-region ------------------
// gemm nd rows now atomicAdd self-conv into loc2 (commutes with pairs atomics,
// loc2 pre-zeroed) -- the separate loc buffer is GONE; k_final reads one row.
__global__ __launch_bounds__(256, 3) void k_main(
        const float* __restrict__ F, const __hip_bfloat16* __restrict__ Wpre,
        const __hip_bfloat16* __restrict__ Wp, const unsigned char* __restrict__ flg,
        const float* __restrict__ g_pre, const float* __restrict__ b_pre,
        const float* __restrict__ g_local, const float* __restrict__ b_local,
        const float* __restrict__ g_norm, const float* __restrict__ b_norm,
        const int* __restrict__ cnt, const int* __restrict__ dst,
        const int* __restrict__ src,
        __hip_bfloat16* __restrict__ F_input, float* __restrict__ loc2,
        float* __restrict__ outp) {
    __shared__ __hip_bfloat16 s_bf[4][16 * 136];   // per-wave F_input staging (gemm)
    __shared__ float s_gp[INC], s_bp[INC], s_gl[INC], s_bl[INC], s_gn[INC], s_bn[INC];
    __shared__ int s_wre[27], s_cntb[26];          // pairs region

    const int tid = threadIdx.x, w = tid >> 6, lane = tid & 63;
    const int q = lane >> 4, l15 = lane & 15;

    if (blockIdx.x >= MT64) {
        // ================= pairs region =================
        const int pb = blockIdx.x - MT64;
        if (tid < 26) { int v = cnt[tid]; if (v > CAPP) v = CAPP; s_cntb[tid] = v; }
        __syncthreads();
        if (tid == 0) {
            int accw = 0; s_wre[0] = 0;
            for (int b = 0; b < 26; ++b) { accw += (s_cntb[b] + 15) >> 4; s_wre[b + 1] = accw; }
        }
        __syncthreads();
        const int W = s_wre[26];
#pragma unroll 1
        for (int wvi = pb * 4 + w; wvi < W; wvi += PAIRB * 4) {
            int b = 0;
            while (wvi >= s_wre[b + 1]) ++b;       // wave-uniform
            int base = (wvi - s_wre[b]) << 4;
            int nB = s_cntb[b];
            int slot = b < 13 ? b : b + 1;
            const int* srcb = src + b * CAPP;
            const int* dstb = dst + b * CAPP;
            int mrow = (base + l15 < nB) ? srcb[base + l15] : 0;
            const bf16x8* Bp = (const bf16x8*)Wp + (size_t)slot * 2048;

            f32x4 acc[8];
#pragma unroll
            for (int j = 0; j < 8; ++j) acc[j] = (f32x4){0.f, 0.f, 0.f, 0.f};
#pragma unroll
            for (int ks = 0; ks < 4; ++ks) {
                bf16x8 a2 = ld_cvt8(F + (size_t)mrow * INC + ks * 32 + q * 8);
#pragma unroll
                for (int j = 0; j < 8; ++j)
                    acc[j] = __builtin_amdgcn_mfma_f32_16x16x32_bf16(
                        a2, Bp[(ks * 8 + j) * 64 + lane], acc[j], 0, 0, 0);
            }
#pragma unroll
            for (int r = 0; r < 4; ++r) {
                int m = (q << 2) + r;
                int ri = base + m;
                if (ri < nB) {
                    int d = dstb[ri];
                    float* lp = loc2 + (size_t)d * INC + l15;
#pragma unroll
                    for (int j = 0; j < 8; ++j) atomicAdd(lp + (j << 4), acc[j][r]);
                }
            }
        }
        return;
    }

    // ================= gemm region =================
    const int p0 = blockIdx.x * 64;

    if (tid < INC) {
        s_gp[tid] = g_pre[tid];   s_bp[tid] = b_pre[tid];
        s_gl[tid] = g_local[tid]; s_bl[tid] = b_local[tid];
        s_gn[tid] = g_norm[tid];  s_bn[tid] = b_norm[tid];
    }
    __syncthreads();

    int grow = p0 + (w << 4) + l15;
    if (grow >= N_PTS) grow = N_PTS - 1;      // clamp; stores guarded

    const float* A = F + (size_t)grow * INC + q * 8;

    // one broadcast 16B flag load for the wave's 16 rows
    const uint32_t* fwp = (const uint32_t*)(flg + p0 + (w << 4));
    uint32_t fq0 = fwp[0], fq1 = fwp[1], fq2 = fwp[2], fq3 = fwp[3];
    uint32_t fqv[4] = {fq0, fq1, fq2, fq3};

    bf16x8 a[4];
#pragma unroll
    for (int ks = 0; ks < 4; ++ks) a[ks] = ld_cvt8(A + ks * 32);

    const bf16x8* BP = (const bf16x8*)Wpre;
    const bf16x8* BL = (const bf16x8*)Wp + (size_t)13 * 2048;
    f32x4 accP[8], accL[8];
#pragma unroll
    for (int j = 0; j < 8; ++j) {
        accP[j] = (f32x4){0.f, 0.f, 0.f, 0.f};
        accL[j] = (f32x4){0.f, 0.f, 0.f, 0.f};
    }
    bf16x8 bP[8], bL[8];
#pragma unroll
    for (int j = 0; j < 8; ++j) bP[j] = BP[j * 64 + lane];
#pragma unroll
    for (int ks = 0; ks < 4; ++ks) {
#pragma unroll
        for (int j = 0; j < 8; ++j) bL[j] = BL[(ks * 8 + j) * 64 + lane];
#pragma unroll
        for (int j = 0; j < 8; ++j)
            accP[j] = __builtin_amdgcn_mfma_f32_16x16x32_bf16(a[ks], bP[j], accP[j], 0, 0, 0);
        if (ks < 3) {
#pragma unroll
            for (int j = 0; j < 8; ++j) bP[j] = BP[((ks + 1) * 8 + j) * 64 + lane];
        }
#pragma unroll
        for (int j = 0; j < 8; ++j)
            accL[j] = __builtin_amdgcn_mfma_f32_16x16x32_bf16(a[ks], bL[j], accL[j], 0, 0, 0);
    }

    __hip_bfloat16* sb = s_bf[w];
#pragma unroll
    for (int r = 0; r < 4; ++r) {
        int ri = (q << 2) + r;
        int p = p0 + (w << 4) + ri;
        int fl = (p < N_PTS) ? (int)((fqv[q] >> (r * 8)) & 1u) : 1;

        float s = 0.f, ss = 0.f;
#pragma unroll
        for (int j = 0; j < 8; ++j) { float v = accP[j][r]; s += v; ss += v * v; }
#pragma unroll
        for (int m = 1; m < 16; m <<= 1) { s += __shfl_xor(s, m); ss += __shfl_xor(ss, m); }
        float mean = s * (1.f / 128.f);
        float rstd = rsqrtf(ss * (1.f / 128.f) - mean * mean + 1e-6f);

        float fj[8], sN = 0.f, ssN = 0.f, sL = 0.f, ssL = 0.f;
#pragma unroll
        for (int j = 0; j < 8; ++j) {
            int c = (j << 4) + l15;
            float fi = (accP[j][r] - mean) * rstd * s_gp[c] + s_bp[c];
            __hip_bfloat16 fb = __float2bfloat16(fi);
            sb[ri * 136 + c] = fb;
            float f = __bfloat162float(fb);
            fj[j] = f; sN += f; ssN += f * f;
            float v = accL[j][r]; sL += v; ssL += v * v;
        }
#pragma unroll
        for (int m = 1; m < 16; m <<= 1) {
            sN += __shfl_xor(sN, m); ssN += __shfl_xor(ssN, m);
            sL += __shfl_xor(sL, m); ssL += __shfl_xor(ssL, m);
        }
        float meanN = sN * (1.f / 128.f);
        float rstdN = rsqrtf(ssN * (1.f / 128.f) - meanN * meanN + 1e-6f);
        float meanL = sL * (1.f / 128.f);
        float rstdL = rsqrtf(ssL * (1.f / 128.f) - meanL * meanL + 1e-6f);

        if (p < N_PTS) {
            if (fl) {
                // nd row: self-conv joins pairs accumulation in loc2
                float* lp = loc2 + (size_t)p * INC;
#pragma unroll
                for (int j = 0; j < 8; ++j) atomicAdd(lp + (j << 4) + l15, accL[j][r]);
            } else {
                float* op2 = outp + (size_t)p * INC;
#pragma unroll
                for (int j = 0; j < 8; ++j) {
                    int c = (j << 4) + l15;
                    float nn = (fj[j] - meanN) * rstdN * s_gn[c] + s_bn[c];
                    float ll = (accL[j][r] - meanL) * rstdL * s_gl[c] + s_bl[c];
                    float o = nn + ll;
                    op2[c] = o > 0.f ? o : 0.f;
                }
            }
        }
    }

#pragma unroll
    for (int t = 0; t < 4; ++t) {
        int row = (t << 2) + q;
        int p = p0 + (w << 4) + row;
        if (p < N_PTS && ((fqv[t] >> (q * 8)) & 1u)) {
            bf16x8 v = *(const bf16x8*)&sb[row * 136 + l15 * 8];
            *(bf16x8*)(F_input + (size_t)p * INC + l15 * 8) = v;
        }
    }
}

// ---------------- K_final: sparse pass; vox via cellmate GATHER -------------
// Register diet: singleton-nd rows have new == F_input EXACTLY (cos^2+sin^2
// cancellation) -> no trig, no w_pos/alpha. Multi path (~4k points) loads
// w_pos/alpha inside the branch and recomputes own trig at the end.
// local = single loc2 row (self atomics from gemm + neighbor atomics).
__global__ __launch_bounds__(256) void k_final(
        const __hip_bfloat16* __restrict__ F_input, const float* __restrict__ loc2,
        const int* __restrict__ nbr_idx, const int* __restrict__ coords,
        const float* __restrict__ counts_v,
        const float* __restrict__ w_pos, const float* __restrict__ alpha,
        const float* __restrict__ g_local, const float* __restrict__ b_local,
        const float* __restrict__ g_norm, const float* __restrict__ b_norm,
        const int* __restrict__ cnt, const int* __restrict__ ndl,
        float* __restrict__ out) {
    const int tid = threadIdx.x, g = tid >> 4, l15 = tid & 15;
    const int c0 = l15 * 8;
    const int nd = cnt[26];
    if (blockIdx.x * 16 >= nd) return;

    float gl[8], bl[8], gn[8], bn[8];
#pragma unroll
    for (int t = 0; t < 2; ++t) {
        ((float4*)gl)[t] = ((const float4*)(g_local + c0))[t];
        ((float4*)bl)[t] = ((const float4*)(b_local + c0))[t];
        ((float4*)gn)[t] = ((const float4*)(g_norm  + c0))[t];
        ((float4*)bn)[t] = ((const float4*)(b_norm  + c0))[t];
    }

    for (int base = blockIdx.x * 16; base < nd; base += gridDim.x * 16) {
        int idx = base + g;
        if (idx >= nd) continue;
        int p = ndl[idx];

        float lv[8], s = 0.f, ss = 0.f;
        ((float4*)lv)[0] = *(const float4*)(loc2 + (size_t)p * INC + c0);
        ((float4*)lv)[1] = *(const float4*)(loc2 + (size_t)p * INC + c0 + 4);
#pragma unroll
        for (int j = 0; j < 8; ++j) { s += lv[j]; ss += lv[j] * lv[j]; }
#pragma unroll
        for (int m = 1; m < 16; m <<= 1) { s += __shfl_xor(s, m); ss += __shfl_xor(ss, m); }
        float meanL = s * (1.f / 128.f);
        float rstdL = rsqrtf(ss * (1.f / 128.f) - meanL * meanL + 1e-6f);

        bf16x8 fbv = *(const bf16x8*)(F_input + (size_t)p * INC + c0);
        float fO[8];
#pragma unroll
        for (int j = 0; j < 8; ++j) fO[j] = __bfloat162float(((__hip_bfloat16*)&fbv)[j]);

        float cv = counts_v[p];
        float nv[8];
        if (cv > 1.5f) {
            // -------- multi: gather cellmates, trig, combine --------
            float invc = 1.f / cv;
            int ix = coords[p * 3 + 0], iy = coords[p * 3 + 1], iz = coords[p * 3 + 2];
            float cx = (float)ix, cy = (float)iy, cz = (float)iz;
            int ox = (ix & 1) ? -1 : 1, oy = (iy & 1) ? -1 : 1, oz = (iz & 1) ? -1 : 1;
            const int* nb = nbr_idx + (size_t)p * NSLOT;

            float wpv[24], pa[8];
#pragma unroll
            for (int t = 0; t < 6; ++t) ((float4*)wpv)[t] = ((const float4*)(w_pos + c0 * 3))[t];
#pragma unroll
            for (int t = 0; t < 2; ++t) ((float4*)pa)[t] = ((const float4*)(alpha + c0))[t];

            unsigned vmask = 1u;
            bf16x8 fmv8[8];
            fmv8[0] = fbv;
#pragma unroll
            for (int e = 1; e < 8; ++e) {
                int dx = (e & 4) ? ox : 0, dy = (e & 2) ? oy : 0, dz = (e & 1) ? oz : 0;
                int m = nb[(dx + 1) * 9 + (dy + 1) * 3 + (dz + 1)];
                bool ok = m < N_PTS;
                if (ok) vmask |= (1u << e);
                int mc = ok ? m : p;
                fmv8[e] = *(const bf16x8*)(F_input + (size_t)mc * INC + c0);
            }
            float v0[8], v1[8], v2[8];
#pragma unroll
            for (int j = 0; j < 8; ++j) { v0[j] = 0.f; v1[j] = 0.f; v2[j] = 0.f; }
#pragma unroll
            for (int e = 0; e < 8; ++e) {
                float wt = ((vmask >> e) & 1u) ? 1.f : 0.f;
                int dx = (e & 4) ? ox : 0, dy = (e & 2) ? oy : 0, dz = (e & 1) ? oz : 0;
                float mx = cx + (float)dx, my = cy + (float)dy, mz = cz + (float)dz;
#pragma unroll
                for (int j = 0; j < 8; ++j) {
                    float fm = wt * __bfloat162float(((__hip_bfloat16*)&fmv8[e])[j]);
                    float ps = compute_pos3(wpv[j * 3], wpv[j * 3 + 1], wpv[j * 3 + 2], pa[j],
                                            mx, my, mz);
                    v0[j] += fm * __cosf(ps);
                    v1[j] += fm * __sinf(ps);
                    v2[j] += fm * ps;
                }
            }
#pragma unroll
            for (int j = 0; j < 8; ++j) {
                float ps = compute_pos3(wpv[j * 3], wpv[j * 3 + 1], wpv[j * 3 + 2], pa[j],
                                        cx, cy, cz);
                float sn = __sinf(ps), cs = __cosf(ps);
                nv[j] = v0[j] * invc * cs + v1[j] * invc * sn + v2[j] * invc - fO[j] * ps;
            }
        } else {
            // -------- singleton-nd: new == F_input (exact cancellation) -----
#pragma unroll
            for (int j = 0; j < 8; ++j) nv[j] = fO[j];
        }

        float s2 = 0.f, ss2 = 0.f;
#pragma unroll
        for (int j = 0; j < 8; ++j) { s2 += nv[j]; ss2 += nv[j] * nv[j]; }
#pragma unroll
        for (int m = 1; m < 16; m <<= 1) { s2 += __shfl_xor(s2, m); ss2 += __shfl_xor(ss2, m); }
        float meanN = s2 * (1.f / 128.f);
        float rstdN = rsqrtf(ss2 * (1.f / 128.f) - meanN * meanN + 1e-6f);
        float ov[8];
#pragma unroll
        for (int j = 0; j < 8; ++j) {
            float nn = (nv[j] - meanN) * rstdN * gn[j] + bn[j];
            float ll = (lv[j] - meanL) * rstdL * gl[j] + bl[j];
            float o = nn + ll;
            ov[j] = o > 0.f ? o : 0.f;
        }
        float4* op = (float4*)(out + (size_t)p * INC + c0);
        op[0] = ((float4*)ov)[0];
        op[1] = ((float4*)ov)[1];
    }
}

// ---------------- host launcher ---------------------------------------------
extern "C" void kernel_launch(void* const* d_in, const int* in_sizes, int n_in,
                              void* d_out, int out_size, void* d_ws, size_t ws_size,
                              hipStream_t stream) {
    (void)in_sizes; (void)n_in; (void)out_size; (void)ws_size;
    const float* F        = (const float*)d_in[0];
    const int*   coords   = (const int*)d_in[1];
    const int*   nbr      = (const int*)d_in[2];
    const float* counts_v = (const float*)d_in[4];
    const float* alpha    = (const float*)d_in[6];
    const float* w_pos    = (const float*)d_in[7];
    const float* w_pre    = (const float*)d_in[8];
    const float* g_pre    = (const float*)d_in[9];
    const float* b_pre    = (const float*)d_in[10];
    const float* w_conv   = (const float*)d_in[11];
    const float* g_local  = (const float*)d_in[12];
    const float* b_local  = (const float*)d_in[13];
    const float* g_norm   = (const float*)d_in[14];
    const float* b_norm   = (const float*)d_in[15];
    float* out = (float*)d_out;

    char* ws = (char*)d_ws;
    __hip_bfloat16* Wp      = (__hip_bfloat16*)(ws + OFF_WP);
    __hip_bfloat16* Wpre    = (__hip_bfloat16*)(ws + OFF_WPRE);
    __hip_bfloat16* F_input = (__hip_bfloat16*)(ws + OFF_FIN);
    float*          loc2    = (float*)(ws + OFF_LOC2);
    int*            cnt     = (int*)(ws + OFF_CNT);
    int*            dstb    = (int*)(ws + OFF_DST);
    int*            srcb    = (int*)(ws + OFF_SRC);
    unsigned char*  flg     = (unsigned char*)(ws + OFF_FLG);
    int*            ndl     = (int*)(ws + OFF_NDL);

    hipMemsetAsync(cnt, 0, SZ_CNT, stream);
    k_front<<<PREP_BLOCKS + SCAN_BLOCKS, 256, 0, stream>>>(
        w_pre, w_conv, Wp, Wpre, nbr, counts_v, cnt, dstb, srcb, flg, ndl, loc2);
    k_main<<<MT64 + PAIRB, 256, 0, stream>>>(
        F, Wpre, Wp, flg, g_pre, b_pre, g_local, b_local, g_norm, b_norm,
        cnt, dstb, srcb, F_input, loc2, out);
    k_final<<<1024, 256, 0, stream>>>(F_input, loc2, nbr, coords, counts_v,
                                      w_pos, alpha, g_local, b_local, g_norm, b_norm,
                                      cnt, ndl, out);
}